// Round 7
// baseline (107.834 us; speedup 1.0000x reference)
//
#include <hip/hip_runtime.h>
#include <hip/hip_bf16.h>

#define N_Q    20
#define DIM    (1 << N_Q)      // 1048576
#define BATCH  4
#define NGATES 19
#define L2OFF  117             // 6n-3 : second xyz layer offset

typedef float2 c32;
typedef __attribute__((ext_vector_type(8))) short short8;
typedef __attribute__((ext_vector_type(4))) float f32x4;
typedef __attribute__((ext_vector_type(4))) unsigned int u32x4;

__device__ __forceinline__ c32 cmul(c32 a, c32 b) {
    return make_float2(fmaf(a.x, b.x, -a.y * b.y), fmaf(a.x, b.y, a.y * b.x));
}
__device__ __forceinline__ c32 cmadd(c32 acc, c32 a, c32 b) {
    acc.x = fmaf(a.x, b.x, fmaf(-a.y, b.y, acc.x));
    acc.y = fmaf(a.x, b.y, fmaf(a.y, b.x, acc.y));
    return acc;
}
__device__ __forceinline__ unsigned short f2bf(float f) {
    union { float f; unsigned u; } v; v.f = f;
    unsigned r = v.u + 0x7FFFu + ((v.u >> 16) & 1u);
    return (unsigned short)(r >> 16);
}
__device__ __forceinline__ void gll16(const void* g, void* l) {
    __builtin_amdgcn_global_load_lds((const __attribute__((address_space(1))) void*)g,
                                     (__attribute__((address_space(3))) void*)l, 16, 0, 0);
}

__device__ void mm2(const c32 A[2][2], const c32 B[2][2], c32 C[2][2]) {
    for (int i = 0; i < 2; i++)
        for (int j = 0; j < 2; j++) {
            c32 s = make_float2(0.f, 0.f);
            for (int k = 0; k < 2; k++) s = cmadd(s, A[i][k], B[k][j]);
            C[i][j] = s;
        }
}
__device__ void mm4(const c32 A[4][4], const c32 B[4][4], c32 C[4][4]) {
    for (int i = 0; i < 4; i++)
        for (int j = 0; j < 4; j++) {
            c32 s = make_float2(0.f, 0.f);
            for (int k = 0; k < 4; k++) s = cmadd(s, A[i][k], B[k][j]);
            C[i][j] = s;
        }
}
__device__ void single_u(const float* w, int base, c32 U[2][2]) {
    const float WM = 0.63245553203367586640f;  // sqrt(2/5)
    float hx = w[base] * WM * 0.5f, hy = w[base + 1] * WM * 0.5f, hz = w[base + 2] * WM * 0.5f;
    float cx = cosf(hx), sx = sinf(hx);
    float cy = cosf(hy), sy = sinf(hy);
    float cz = cosf(hz), sz = sinf(hz);
    c32 RX[2][2] = {{{cx, 0.f}, {0.f, -sx}}, {{0.f, -sx}, {cx, 0.f}}};
    c32 RY[2][2] = {{{cy, 0.f}, {-sy, 0.f}}, {{sy, 0.f}, {cy, 0.f}}};
    c32 RZ[2][2] = {{{cz, -sz}, {0.f, 0.f}}, {{0.f, 0.f}, {cz, sz}}};
    c32 T[2][2];
    mm2(RY, RX, T);
    mm2(RZ, T, U);
}
__device__ void kron22(const c32 A[2][2], const c32 B[2][2], c32 K[4][4]) {
    for (int i = 0; i < 2; i++)
        for (int j = 0; j < 2; j++)
            for (int k = 0; k < 2; k++)
                for (int l = 0; l < 2; l++)
                    K[i * 2 + j][k * 2 + l] = cmul(A[i][k], B[j][l]);
}

// Build the 19 fused 4x4 staircase gates (round-0 derivation).
__global__ void build_gates(const float* __restrict__ w, c32* __restrict__ G) {
    int q = threadIdx.x;
    if (q >= NGATES) return;
    const float WM = 0.63245553203367586640f;
    float hx = w[60 + 3 * q] * WM * 0.5f;
    float hy = w[61 + 3 * q] * WM * 0.5f;
    float hz = w[62 + 3 * q] * WM * 0.5f;
    float cx = cosf(hx), sx = sinf(hx);
    float cy = cosf(hy), sy = sinf(hy);
    float cz = cosf(hz), sz = sinf(hz);
    c32 RXX[4][4], RYY[4][4], RZZ[4][4];
    for (int i = 0; i < 4; i++)
        for (int j = 0; j < 4; j++) {
            RXX[i][j] = make_float2(0.f, 0.f);
            RYY[i][j] = make_float2(0.f, 0.f);
            RZZ[i][j] = make_float2(0.f, 0.f);
        }
    for (int i = 0; i < 4; i++) {
        RXX[i][i]     = make_float2(cx, 0.f);
        RXX[i][3 - i] = make_float2(0.f, -sx);
        RYY[i][i]     = make_float2(cy, 0.f);
    }
    RYY[0][3] = make_float2(0.f,  sy);
    RYY[1][2] = make_float2(0.f, -sy);
    RYY[2][1] = make_float2(0.f, -sy);
    RYY[3][0] = make_float2(0.f,  sy);
    RZZ[0][0] = make_float2(cz, -sz);
    RZZ[1][1] = make_float2(cz,  sz);
    RZZ[2][2] = make_float2(cz,  sz);
    RZZ[3][3] = make_float2(cz, -sz);
    c32 T[4][4], M[4][4];
    mm4(RYY, RXX, T);
    mm4(RZZ, T, M);

    c32 I2m[2][2] = {{{1.f, 0.f}, {0.f, 0.f}}, {{0.f, 0.f}, {1.f, 0.f}}};
    c32 Ua[2][2], Ub[2][2], Pre[4][4], Post[4][4];
    if (q == 0) {
        single_u(w, 0, Ua);
        single_u(w, 3, Ub);
        kron22(Ua, Ub, Pre);
    } else {
        single_u(w, 3 * (q + 1), Ub);
        kron22(I2m, Ub, Pre);
    }
    if (q == NGATES - 1) {
        single_u(w, L2OFF + 3 * 18, Ua);
        single_u(w, L2OFF + 3 * 19, Ub);
        kron22(Ua, Ub, Post);
    } else {
        single_u(w, L2OFF + 3 * q, Ua);
        kron22(Ua, I2m, Post);
    }
    c32 T2[4][4], Gq[4][4];
    mm4(M, Pre, T2);
    mm4(Post, T2, Gq);
    for (int i = 0; i < 4; i++)
        for (int j = 0; j < 4; j++)
            G[q * 16 + i * 4 + j] = Gq[i][j];
}

__device__ __forceinline__ void apply4(const c32* g, c32& x0, c32& x1, c32& x2, c32& x3) {
    c32 r0 = cmul(g[0],  x0); r0 = cmadd(r0, g[1],  x1); r0 = cmadd(r0, g[2],  x2); r0 = cmadd(r0, g[3],  x3);
    c32 r1 = cmul(g[4],  x0); r1 = cmadd(r1, g[5],  x1); r1 = cmadd(r1, g[6],  x2); r1 = cmadd(r1, g[7],  x3);
    c32 r2 = cmul(g[8],  x0); r2 = cmadd(r2, g[9],  x1); r2 = cmadd(r2, g[10], x2); r2 = cmadd(r2, g[11], x3);
    c32 r3 = cmul(g[12], x0); r3 = cmadd(r3, g[13], x1); r3 = cmadd(r3, g[14], x2); r3 = cmadd(r3, g[15], x3);
    x0 = r0; x1 = r1; x2 = r2; x3 = r3;
}
__device__ __forceinline__ void load_gate(const c32* __restrict__ gp, c32 g[16]) {
#pragma unroll
    for (int k = 0; k < 16; k++) g[k] = gp[k];
}
template <int LO>
__device__ __forceinline__ void gate_on32(c32 v[32], const c32 g[16]) {
#pragma unroll
    for (int m = 0; m < 8; ++m) {
        const int j0 = ((m >> LO) << (LO + 2)) | (m & ((1 << LO) - 1));
        const int s = 1 << LO;
        apply4(g, v[j0], v[j0 + s], v[j0 + 2 * s], v[j0 + 3 * s]);
    }
}
template <int LO>
__device__ __forceinline__ void gate_on16(c32* v, const c32 g[16]) {
#pragma unroll
    for (int m = 0; m < 4; ++m) {
        const int j0 = ((m >> LO) << (LO + 2)) | (m & ((1 << LO) - 1));
        const int s = 1 << LO;
        apply4(g, v[j0], v[j0 + s], v[j0 + 2 * s], v[j0 + 3 * s]);
    }
}

// XOR swizzle for 8192-c32 LDS exchanges (verified <=4-way for all patterns used).
#define SIDX(l) ((l) ^ ((((l) >> 5) & 15)))

// Pass A2: gates 0..6 (psi bits 19..12). State = [256 rows = bits 19..12][4096 cols].
__global__ __launch_bounds__(256) void pass_a2(const float* __restrict__ x,
                                               c32* __restrict__ psi,
                                               const c32* __restrict__ Gall) {
    __shared__ __align__(16) char smem[65536];
    float* xs = (float*)smem;        // [256][32] f32, 16B-slot swizzled (32 KB)
    c32* s = (c32*)smem;             // 8192 c32 exchange view (64 KB)
    int b = blockIdx.x >> 7;
    int c0 = (blockIdx.x & 127) << 5;
    const float* xp = x + ((size_t)b << 20) + c0;
    c32* pp = psi + ((size_t)b << 20) + c0;
    int t = threadIdx.x;
#pragma unroll
    for (int i = 0; i < 8; ++i) {
        int f4 = t + (i << 8);
        int row = f4 >> 3, sl = f4 & 7;
        float4 v = *reinterpret_cast<const float4*>(xp + (size_t)row * 4096 + sl * 4);
        reinterpret_cast<float4*>(xs)[row * 8 + (sl ^ (row & 7))] = v;
    }
    __syncthreads();
    int col = t & 31, rlow = t >> 5;
    c32 v[32], g[16];
#pragma unroll
    for (int j = 0; j < 32; ++j) {
        int row = (j << 3) | rlow;
        float re = xs[row * 32 + ((((col >> 2) ^ (row & 7)) << 2) | (col & 3))];
        v[j] = make_float2(re, 0.f);
    }
    __syncthreads();
    load_gate(Gall + 0 * 16, g);  gate_on32<3>(v, g);
    load_gate(Gall + 1 * 16, g);  gate_on32<2>(v, g);
    load_gate(Gall + 2 * 16, g);  gate_on32<1>(v, g);
    load_gate(Gall + 3 * 16, g);  gate_on32<0>(v, g);
#pragma unroll
    for (int j = 0; j < 32; ++j) {
        int l = ((((j << 3) | rlow) << 5)) | col;
        s[SIDX(l)] = v[j];
    }
    __syncthreads();
    int rhi = t >> 5;
#pragma unroll
    for (int rtop = 0; rtop < 2; ++rtop)
#pragma unroll
        for (int j = 0; j < 16; ++j) {
            int row = (rtop << 7) | (rhi << 4) | j;
            int l = (row << 5) | col;
            v[rtop * 16 + j] = s[SIDX(l)];
        }
    load_gate(Gall + 4 * 16, g);  gate_on16<2>(v, g);  gate_on16<2>(v + 16, g);
    load_gate(Gall + 5 * 16, g);  gate_on16<1>(v, g);  gate_on16<1>(v + 16, g);
    load_gate(Gall + 6 * 16, g);  gate_on16<0>(v, g);  gate_on16<0>(v + 16, g);
#pragma unroll
    for (int rtop = 0; rtop < 2; ++rtop)
#pragma unroll
        for (int j = 0; j < 16; ++j) {
            int row = (rtop << 7) | (rhi << 4) | j;
            pp[(size_t)row * 4096 + col] = v[rtop * 16 + j];
        }
}

// Pass B2: gates 7..18 (psi bits 12..0). 3 register phases, 2 LDS exchanges;
// writes planar bf16 [t][a] (Brt, Bit).
__global__ __launch_bounds__(256) void pass_b2(const c32* __restrict__ psi,
                                               unsigned short* __restrict__ Brt,
                                               unsigned short* __restrict__ Bit,
                                               const c32* __restrict__ Gall) {
    __shared__ c32 s[8192];
    int b = blockIdx.x >> 7;
    int chunk = blockIdx.x & 127;
    const c32* pp = psi + ((size_t)b << 20) + ((size_t)chunk << 13);
    int t = threadIdx.x;
    c32 v[32], g[16];
#pragma unroll
    for (int j = 0; j < 32; ++j) v[j] = pp[(j << 8) | t];
    load_gate(Gall + 7 * 16, g);   gate_on32<3>(v, g);
    load_gate(Gall + 8 * 16, g);   gate_on32<2>(v, g);
    load_gate(Gall + 9 * 16, g);   gate_on32<1>(v, g);
    load_gate(Gall + 10 * 16, g);  gate_on32<0>(v, g);
#pragma unroll
    for (int j = 0; j < 32; ++j) { int l = (j << 8) | t; s[SIDX(l)] = v[j]; }
    __syncthreads();
    int hi2 = (t >> 4) << 9, lo2 = t & 15;
#pragma unroll
    for (int j = 0; j < 32; ++j) { int l = hi2 | (j << 4) | lo2; v[j] = s[SIDX(l)]; }
    load_gate(Gall + 11 * 16, g);  gate_on32<3>(v, g);
    load_gate(Gall + 12 * 16, g);  gate_on32<2>(v, g);
    load_gate(Gall + 13 * 16, g);  gate_on32<1>(v, g);
    load_gate(Gall + 14 * 16, g);  gate_on32<0>(v, g);
    __syncthreads();
#pragma unroll
    for (int j = 0; j < 32; ++j) { int l = hi2 | (j << 4) | lo2; s[SIDX(l)] = v[j]; }
    __syncthreads();
#pragma unroll
    for (int j = 0; j < 32; ++j) { int l = (t << 5) | j; v[j] = s[SIDX(l)]; }
    load_gate(Gall + 15 * 16, g);  gate_on32<3>(v, g);
    load_gate(Gall + 16 * 16, g);  gate_on32<2>(v, g);
    load_gate(Gall + 17 * 16, g);  gate_on32<1>(v, g);
    load_gate(Gall + 18 * 16, g);  gate_on32<0>(v, g);
    size_t off = ((size_t)b << 20) + ((size_t)chunk << 13) + ((size_t)t << 5);
#pragma unroll
    for (int p = 0; p < 4; ++p) {
        unsigned short rr[8], ri[8];
#pragma unroll
        for (int i = 0; i < 8; ++i) {
            rr[i] = f2bf(v[8 * p + i].x);
            ri[i] = f2bf(v[8 * p + i].y);
        }
        *reinterpret_cast<float4*>(Brt + off + 8 * p) = *reinterpret_cast<float4*>(rr);
        *reinterpret_cast<float4*>(Bit + off + 8 * p) = *reinterpret_cast<float4*>(ri);
    }
}

// bf16 transpose: B[t][a] -> A[a][t] for both planes, merged as u32 in LDS.
__global__ __launch_bounds__(256) void bt_t(const unsigned short* __restrict__ Brt,
                                            const unsigned short* __restrict__ Bit,
                                            unsigned short* __restrict__ Art,
                                            unsigned short* __restrict__ Ait) {
    __shared__ unsigned lds32[64 * 66];
    int b  = blockIdx.z;
    int t0 = blockIdx.x * 64;
    int a0 = blockIdx.y * 64;
    size_t gb = (size_t)b << 20;
#pragma unroll
    for (int h = 0; h < 2; ++h) {
        int p = threadIdx.x + h * 256;
        int r = p >> 3, cq = p & 7;
        size_t src = gb + (size_t)(t0 + r) * 1024 + a0 + cq * 8;
        float4 fr = *reinterpret_cast<const float4*>(Brt + src);
        float4 fi = *reinterpret_cast<const float4*>(Bit + src);
        const unsigned short* ur = reinterpret_cast<const unsigned short*>(&fr);
        const unsigned short* ui = reinterpret_cast<const unsigned short*>(&fi);
#pragma unroll
        for (int i = 0; i < 8; ++i)
            lds32[r * 66 + cq * 8 + i] = (unsigned)ur[i] | ((unsigned)ui[i] << 16);
    }
    __syncthreads();
#pragma unroll
    for (int h = 0; h < 2; ++h) {
        int q = threadIdx.x + h * 256;
        int a = q >> 3, tq = q & 7;
        unsigned short rr[8], ri[8];
#pragma unroll
        for (int i = 0; i < 8; ++i) {
            unsigned w = lds32[(tq * 8 + i) * 66 + a];
            rr[i] = (unsigned short)(w & 0xFFFF);
            ri[i] = (unsigned short)(w >> 16);
        }
        size_t dst = gb + (size_t)(a0 + a) * 1024 + t0 + tq * 8;
        *reinterpret_cast<float4*>(Art + dst) = *reinterpret_cast<float4*>(rr);
        *reinterpret_cast<float4*>(Ait + dst) = *reinterpret_cast<float4*>(ri);
    }
}

// gram_mfma4: residency-first structure. 512 threads (8 waves), single 32 KB LDS
// buffer, plain __syncthreads. Wave w: output quadrant q=w&3 (32x32), K-half
// kk0=w>>2 (partial sums). End: kk0=1 waves push partial accs through LDS to
// kk0=0 waves. XCD-swizzled block order (544 = 8*68) colocates panel-sharing
// tiles per XCD L2.
__global__ __launch_bounds__(512) void gram_mfma4(const unsigned short* __restrict__ Art,
                                                  const unsigned short* __restrict__ Ait,
                                                  float2* __restrict__ out) {
    __shared__ __align__(16) unsigned short lds[4][4096];   // 32 KB: {aR,aI,cR,cI}[64][64]
    int hw = blockIdx.y * 136 + blockIdx.x;
    int virt = (hw & 7) * 68 + (hw >> 3);        // bijective: 544 = 8*68
    int b = virt / 136;
    int rem = virt - b * 136;                    // triangular decode, ia <= ic
    int ia = 0;
    while (rem >= 16 - ia) { rem -= 16 - ia; ++ia; }
    int ic = ia + rem;
    int a0 = ia * 64, c0 = ic * 64;
    int tid = threadIdx.x;
    int lane = tid & 63, w = tid >> 6;           // 8 waves
    int q = w & 3, kk0 = w >> 2;
    int wr = (q >> 1) * 32, wc = (q & 1) * 32;
    // staging role: array = w>>1 (0..3), row-half = w&1
    int arr = w >> 1, half = w & 1;
    const unsigned short* sp = (arr & 1) ? Ait : Art;
    int prow = (arr < 2) ? a0 : c0;
    int srow = lane >> 3, sslot = lane & 7;
    size_t gb = (size_t)b << 20;

    f32x4 accRe[2][2], accIm[2][2];
#pragma unroll
    for (int m = 0; m < 2; m++)
#pragma unroll
        for (int n = 0; n < 2; n++) { accRe[m][n] = (f32x4)0.f; accIm[m][n] = (f32x4)0.f; }

    for (int kt = 0; kt < 16; ++kt) {
        // stage this wave's 4 KB: rows r = half*32 + i*8 + srow, source slot ^= (r&7)
#pragma unroll
        for (int i = 0; i < 4; ++i) {
            int r = (half << 5) | (i << 3) | srow;
            int sl = sslot ^ srow;
            const unsigned short* gp = sp + gb + ((size_t)(prow + r) << 10) + kt * 64 + sl * 8;
            gll16(gp, &lds[arr][(half << 11) + (i << 9) + lane * 8]);
        }
        __syncthreads();
        {
            int sbase = kk0 * 4 + (lane >> 4);   // 16B-slot 0..7 (this wave's K-half)
            short8 ar[2], ai[2], br[2], bi[2];
#pragma unroll
            for (int m = 0; m < 2; m++) {
                int r = wr + m * 16 + (lane & 15);
                int off = r * 64 + ((sbase ^ (r & 7)) << 3);
                ar[m] = *reinterpret_cast<const short8*>(&lds[0][off]);
                ai[m] = *reinterpret_cast<const short8*>(&lds[1][off]);
            }
#pragma unroll
            for (int n = 0; n < 2; n++) {
                int r = wc + n * 16 + (lane & 15);
                int off = r * 64 + ((sbase ^ (r & 7)) << 3);
                br[n] = *reinterpret_cast<const short8*>(&lds[2][off]);
                bi[n] = *reinterpret_cast<const short8*>(&lds[3][off]);
            }
#pragma unroll
            for (int m = 0; m < 2; m++) {
                u32x4 tn = *reinterpret_cast<u32x4*>(&ar[m]) ^ 0x80008000u;
                short8 arn = *reinterpret_cast<short8*>(&tn);
#pragma unroll
                for (int n = 0; n < 2; n++) {
                    accRe[m][n] = __builtin_amdgcn_mfma_f32_16x16x32_bf16(ar[m],  br[n], accRe[m][n], 0, 0, 0);
                    accRe[m][n] = __builtin_amdgcn_mfma_f32_16x16x32_bf16(ai[m],  bi[n], accRe[m][n], 0, 0, 0);
                    accIm[m][n] = __builtin_amdgcn_mfma_f32_16x16x32_bf16(ai[m],  br[n], accIm[m][n], 0, 0, 0);
                    accIm[m][n] = __builtin_amdgcn_mfma_f32_16x16x32_bf16(arn,    bi[n], accIm[m][n], 0, 0, 0);
                }
            }
        }
        __syncthreads();   // buffer reuse next kt
    }
    // combine K-halves: kk0=1 waves -> LDS -> kk0=0 waves
    float* xch = reinterpret_cast<float*>(&lds[0][0]);   // 8192 f32 capacity, exact fit
    if (kk0 == 1) {
        float* dst = xch + q * 2048 + lane * 4;
        int idx = 0;
#pragma unroll
        for (int m = 0; m < 2; m++)
#pragma unroll
            for (int n = 0; n < 2; n++) { *reinterpret_cast<f32x4*>(dst + idx * 256) = accRe[m][n]; idx++; }
#pragma unroll
        for (int m = 0; m < 2; m++)
#pragma unroll
            for (int n = 0; n < 2; n++) { *reinterpret_cast<f32x4*>(dst + idx * 256) = accIm[m][n]; idx++; }
    }
    __syncthreads();
    if (kk0 == 0) {
        float* src = xch + q * 2048 + lane * 4;
        int idx = 0;
#pragma unroll
        for (int m = 0; m < 2; m++)
#pragma unroll
            for (int n = 0; n < 2; n++) { accRe[m][n] += *reinterpret_cast<f32x4*>(src + idx * 256); idx++; }
#pragma unroll
        for (int m = 0; m < 2; m++)
#pragma unroll
            for (int n = 0; n < 2; n++) { accIm[m][n] += *reinterpret_cast<f32x4*>(src + idx * 256); idx++; }
        // C/D layout: col = lane&15, row = (lane>>4)*4 + reg
        size_t ob = (size_t)b << 20;
#pragma unroll
        for (int m = 0; m < 2; m++)
#pragma unroll
            for (int n = 0; n < 2; n++)
#pragma unroll
                for (int r = 0; r < 4; r++) {
                    int a = a0 + wr + m * 16 + (lane >> 4) * 4 + r;
                    int c = c0 + wc + n * 16 + (lane & 15);
                    float re = accRe[m][n][r];
                    float im = accIm[m][n][r];
                    out[ob + ((size_t)a << 10) + c] = make_float2(re, im);
                    if (ia != ic)
                        out[ob + ((size_t)c << 10) + a] = make_float2(re, -im);
                }
    }
}

extern "C" void kernel_launch(void* const* d_in, const int* in_sizes, int n_in,
                              void* d_out, int out_size, void* d_ws, size_t ws_size,
                              hipStream_t stream) {
    const float* x = (const float*)d_in[0];
    const float* weight = (const float*)d_in[1];
    const size_t psiBytes = (size_t)BATCH * DIM * sizeof(c32);       // 32 MB
    c32* psi = (c32*)d_ws;
    c32* G = (c32*)((char*)d_ws + psiBytes);
    unsigned short* Brt = (unsigned short*)((char*)d_ws + psiBytes + 65536);
    unsigned short* Bit = Brt + (size_t)BATCH * DIM;
    unsigned short* Art = Bit + (size_t)BATCH * DIM;
    unsigned short* Ait = Art + (size_t)BATCH * DIM;

    build_gates<<<1, 64, 0, stream>>>(weight, G);
    pass_a2<<<BATCH * 128, 256, 0, stream>>>(x, psi, G);            // gates 0..6
    pass_b2<<<BATCH * 128, 256, 0, stream>>>(psi, Brt, Bit, G);     // gates 7..18 -> bf16 [t][a]
    bt_t<<<dim3(16, 16, BATCH), 256, 0, stream>>>(Brt, Bit, Art, Ait);
    gram_mfma4<<<dim3(136, BATCH), 512, 0, stream>>>(Art, Ait, (float2*)d_out);
}

// Round 8
// 106.522 us; speedup vs baseline: 1.0123x; 1.0123x over previous
//
#include <hip/hip_runtime.h>
#include <hip/hip_bf16.h>

#define N_Q    20
#define DIM    (1 << N_Q)      // 1048576
#define BATCH  4
#define NGATES 19
#define L2OFF  117             // 6n-3 : second xyz layer offset

typedef float2 c32;
typedef __attribute__((ext_vector_type(8))) short short8;
typedef __attribute__((ext_vector_type(4))) float f32x4;
typedef __attribute__((ext_vector_type(4))) unsigned int u32x4;

__device__ __forceinline__ c32 cmul(c32 a, c32 b) {
    return make_float2(fmaf(a.x, b.x, -a.y * b.y), fmaf(a.x, b.y, a.y * b.x));
}
__device__ __forceinline__ c32 cmadd(c32 acc, c32 a, c32 b) {
    acc.x = fmaf(a.x, b.x, fmaf(-a.y, b.y, acc.x));
    acc.y = fmaf(a.x, b.y, fmaf(a.y, b.x, acc.y));
    return acc;
}
__device__ __forceinline__ unsigned short f2bf(float f) {
    union { float f; unsigned u; } v; v.f = f;
    unsigned r = v.u + 0x7FFFu + ((v.u >> 16) & 1u);
    return (unsigned short)(r >> 16);
}
__device__ __forceinline__ void gll16(const void* g, void* l) {
    __builtin_amdgcn_global_load_lds((const __attribute__((address_space(1))) void*)g,
                                     (__attribute__((address_space(3))) void*)l, 16, 0, 0);
}

__device__ void mm2(const c32 A[2][2], const c32 B[2][2], c32 C[2][2]) {
    for (int i = 0; i < 2; i++)
        for (int j = 0; j < 2; j++) {
            c32 s = make_float2(0.f, 0.f);
            for (int k = 0; k < 2; k++) s = cmadd(s, A[i][k], B[k][j]);
            C[i][j] = s;
        }
}
__device__ void mm4(const c32 A[4][4], const c32 B[4][4], c32 C[4][4]) {
    for (int i = 0; i < 4; i++)
        for (int j = 0; j < 4; j++) {
            c32 s = make_float2(0.f, 0.f);
            for (int k = 0; k < 4; k++) s = cmadd(s, A[i][k], B[k][j]);
            C[i][j] = s;
        }
}
__device__ void single_u(const float* w, int base, c32 U[2][2]) {
    const float WM = 0.63245553203367586640f;  // sqrt(2/5)
    float hx = w[base] * WM * 0.5f, hy = w[base + 1] * WM * 0.5f, hz = w[base + 2] * WM * 0.5f;
    float cx = cosf(hx), sx = sinf(hx);
    float cy = cosf(hy), sy = sinf(hy);
    float cz = cosf(hz), sz = sinf(hz);
    c32 RX[2][2] = {{{cx, 0.f}, {0.f, -sx}}, {{0.f, -sx}, {cx, 0.f}}};
    c32 RY[2][2] = {{{cy, 0.f}, {-sy, 0.f}}, {{sy, 0.f}, {cy, 0.f}}};
    c32 RZ[2][2] = {{{cz, -sz}, {0.f, 0.f}}, {{0.f, 0.f}, {cz, sz}}};
    c32 T[2][2];
    mm2(RY, RX, T);
    mm2(RZ, T, U);
}
__device__ void kron22(const c32 A[2][2], const c32 B[2][2], c32 K[4][4]) {
    for (int i = 0; i < 2; i++)
        for (int j = 0; j < 2; j++)
            for (int k = 0; k < 2; k++)
                for (int l = 0; l < 2; l++)
                    K[i * 2 + j][k * 2 + l] = cmul(A[i][k], B[j][l]);
}

// Build the 19 fused 4x4 staircase gates (round-0 derivation).
__global__ void build_gates(const float* __restrict__ w, c32* __restrict__ G) {
    int q = threadIdx.x;
    if (q >= NGATES) return;
    const float WM = 0.63245553203367586640f;
    float hx = w[60 + 3 * q] * WM * 0.5f;
    float hy = w[61 + 3 * q] * WM * 0.5f;
    float hz = w[62 + 3 * q] * WM * 0.5f;
    float cx = cosf(hx), sx = sinf(hx);
    float cy = cosf(hy), sy = sinf(hy);
    float cz = cosf(hz), sz = sinf(hz);
    c32 RXX[4][4], RYY[4][4], RZZ[4][4];
    for (int i = 0; i < 4; i++)
        for (int j = 0; j < 4; j++) {
            RXX[i][j] = make_float2(0.f, 0.f);
            RYY[i][j] = make_float2(0.f, 0.f);
            RZZ[i][j] = make_float2(0.f, 0.f);
        }
    for (int i = 0; i < 4; i++) {
        RXX[i][i]     = make_float2(cx, 0.f);
        RXX[i][3 - i] = make_float2(0.f, -sx);
        RYY[i][i]     = make_float2(cy, 0.f);
    }
    RYY[0][3] = make_float2(0.f,  sy);
    RYY[1][2] = make_float2(0.f, -sy);
    RYY[2][1] = make_float2(0.f, -sy);
    RYY[3][0] = make_float2(0.f,  sy);
    RZZ[0][0] = make_float2(cz, -sz);
    RZZ[1][1] = make_float2(cz,  sz);
    RZZ[2][2] = make_float2(cz,  sz);
    RZZ[3][3] = make_float2(cz, -sz);
    c32 T[4][4], M[4][4];
    mm4(RYY, RXX, T);
    mm4(RZZ, T, M);

    c32 I2m[2][2] = {{{1.f, 0.f}, {0.f, 0.f}}, {{0.f, 0.f}, {1.f, 0.f}}};
    c32 Ua[2][2], Ub[2][2], Pre[4][4], Post[4][4];
    if (q == 0) {
        single_u(w, 0, Ua);
        single_u(w, 3, Ub);
        kron22(Ua, Ub, Pre);
    } else {
        single_u(w, 3 * (q + 1), Ub);
        kron22(I2m, Ub, Pre);
    }
    if (q == NGATES - 1) {
        single_u(w, L2OFF + 3 * 18, Ua);
        single_u(w, L2OFF + 3 * 19, Ub);
        kron22(Ua, Ub, Post);
    } else {
        single_u(w, L2OFF + 3 * q, Ua);
        kron22(Ua, I2m, Post);
    }
    c32 T2[4][4], Gq[4][4];
    mm4(M, Pre, T2);
    mm4(Post, T2, Gq);
    for (int i = 0; i < 4; i++)
        for (int j = 0; j < 4; j++)
            G[q * 16 + i * 4 + j] = Gq[i][j];
}

__device__ __forceinline__ void apply4(const c32* g, c32& x0, c32& x1, c32& x2, c32& x3) {
    c32 r0 = cmul(g[0],  x0); r0 = cmadd(r0, g[1],  x1); r0 = cmadd(r0, g[2],  x2); r0 = cmadd(r0, g[3],  x3);
    c32 r1 = cmul(g[4],  x0); r1 = cmadd(r1, g[5],  x1); r1 = cmadd(r1, g[6],  x2); r1 = cmadd(r1, g[7],  x3);
    c32 r2 = cmul(g[8],  x0); r2 = cmadd(r2, g[9],  x1); r2 = cmadd(r2, g[10], x2); r2 = cmadd(r2, g[11], x3);
    c32 r3 = cmul(g[12], x0); r3 = cmadd(r3, g[13], x1); r3 = cmadd(r3, g[14], x2); r3 = cmadd(r3, g[15], x3);
    x0 = r0; x1 = r1; x2 = r2; x3 = r3;
}
__device__ __forceinline__ void load_gate(const c32* __restrict__ gp, c32 g[16]) {
#pragma unroll
    for (int k = 0; k < 16; k++) g[k] = gp[k];
}
template <int LO>
__device__ __forceinline__ void gate_on32(c32 v[32], const c32 g[16]) {
#pragma unroll
    for (int m = 0; m < 8; ++m) {
        const int j0 = ((m >> LO) << (LO + 2)) | (m & ((1 << LO) - 1));
        const int s = 1 << LO;
        apply4(g, v[j0], v[j0 + s], v[j0 + 2 * s], v[j0 + 3 * s]);
    }
}
template <int LO>
__device__ __forceinline__ void gate_on16(c32* v, const c32 g[16]) {
#pragma unroll
    for (int m = 0; m < 4; ++m) {
        const int j0 = ((m >> LO) << (LO + 2)) | (m & ((1 << LO) - 1));
        const int s = 1 << LO;
        apply4(g, v[j0], v[j0 + s], v[j0 + 2 * s], v[j0 + 3 * s]);
    }
}

// XOR swizzle for 8192-c32 LDS exchanges (verified <=4-way for all patterns used).
#define SIDX(l) ((l) ^ ((((l) >> 5) & 15)))

// Pass A2: gates 0..6 (psi bits 19..12). State = [256 rows = bits 19..12][4096 cols].
__global__ __launch_bounds__(256) void pass_a2(const float* __restrict__ x,
                                               c32* __restrict__ psi,
                                               const c32* __restrict__ Gall) {
    __shared__ __align__(16) char smem[65536];
    float* xs = (float*)smem;        // [256][32] f32, 16B-slot swizzled (32 KB)
    c32* s = (c32*)smem;             // 8192 c32 exchange view (64 KB)
    int b = blockIdx.x >> 7;
    int c0 = (blockIdx.x & 127) << 5;
    const float* xp = x + ((size_t)b << 20) + c0;
    c32* pp = psi + ((size_t)b << 20) + c0;
    int t = threadIdx.x;
#pragma unroll
    for (int i = 0; i < 8; ++i) {
        int f4 = t + (i << 8);
        int row = f4 >> 3, sl = f4 & 7;
        float4 v = *reinterpret_cast<const float4*>(xp + (size_t)row * 4096 + sl * 4);
        reinterpret_cast<float4*>(xs)[row * 8 + (sl ^ (row & 7))] = v;
    }
    __syncthreads();
    int col = t & 31, rlow = t >> 5;
    c32 v[32], g[16];
#pragma unroll
    for (int j = 0; j < 32; ++j) {
        int row = (j << 3) | rlow;
        float re = xs[row * 32 + ((((col >> 2) ^ (row & 7)) << 2) | (col & 3))];
        v[j] = make_float2(re, 0.f);
    }
    __syncthreads();
    load_gate(Gall + 0 * 16, g);  gate_on32<3>(v, g);
    load_gate(Gall + 1 * 16, g);  gate_on32<2>(v, g);
    load_gate(Gall + 2 * 16, g);  gate_on32<1>(v, g);
    load_gate(Gall + 3 * 16, g);  gate_on32<0>(v, g);
#pragma unroll
    for (int j = 0; j < 32; ++j) {
        int l = ((((j << 3) | rlow) << 5)) | col;
        s[SIDX(l)] = v[j];
    }
    __syncthreads();
    int rhi = t >> 5;
#pragma unroll
    for (int rtop = 0; rtop < 2; ++rtop)
#pragma unroll
        for (int j = 0; j < 16; ++j) {
            int row = (rtop << 7) | (rhi << 4) | j;
            int l = (row << 5) | col;
            v[rtop * 16 + j] = s[SIDX(l)];
        }
    load_gate(Gall + 4 * 16, g);  gate_on16<2>(v, g);  gate_on16<2>(v + 16, g);
    load_gate(Gall + 5 * 16, g);  gate_on16<1>(v, g);  gate_on16<1>(v + 16, g);
    load_gate(Gall + 6 * 16, g);  gate_on16<0>(v, g);  gate_on16<0>(v + 16, g);
#pragma unroll
    for (int rtop = 0; rtop < 2; ++rtop)
#pragma unroll
        for (int j = 0; j < 16; ++j) {
            int row = (rtop << 7) | (rhi << 4) | j;
            pp[(size_t)row * 4096 + col] = v[rtop * 16 + j];
        }
}

// Pass B2: gates 7..18 (psi bits 12..0). 3 register phases, 2 LDS exchanges;
// writes planar bf16 [t][a] (Brt, Bit).
__global__ __launch_bounds__(256) void pass_b2(const c32* __restrict__ psi,
                                               unsigned short* __restrict__ Brt,
                                               unsigned short* __restrict__ Bit,
                                               const c32* __restrict__ Gall) {
    __shared__ c32 s[8192];
    int b = blockIdx.x >> 7;
    int chunk = blockIdx.x & 127;
    const c32* pp = psi + ((size_t)b << 20) + ((size_t)chunk << 13);
    int t = threadIdx.x;
    c32 v[32], g[16];
#pragma unroll
    for (int j = 0; j < 32; ++j) v[j] = pp[(j << 8) | t];
    load_gate(Gall + 7 * 16, g);   gate_on32<3>(v, g);
    load_gate(Gall + 8 * 16, g);   gate_on32<2>(v, g);
    load_gate(Gall + 9 * 16, g);   gate_on32<1>(v, g);
    load_gate(Gall + 10 * 16, g);  gate_on32<0>(v, g);
#pragma unroll
    for (int j = 0; j < 32; ++j) { int l = (j << 8) | t; s[SIDX(l)] = v[j]; }
    __syncthreads();
    int hi2 = (t >> 4) << 9, lo2 = t & 15;
#pragma unroll
    for (int j = 0; j < 32; ++j) { int l = hi2 | (j << 4) | lo2; v[j] = s[SIDX(l)]; }
    load_gate(Gall + 11 * 16, g);  gate_on32<3>(v, g);
    load_gate(Gall + 12 * 16, g);  gate_on32<2>(v, g);
    load_gate(Gall + 13 * 16, g);  gate_on32<1>(v, g);
    load_gate(Gall + 14 * 16, g);  gate_on32<0>(v, g);
    __syncthreads();
#pragma unroll
    for (int j = 0; j < 32; ++j) { int l = hi2 | (j << 4) | lo2; s[SIDX(l)] = v[j]; }
    __syncthreads();
#pragma unroll
    for (int j = 0; j < 32; ++j) { int l = (t << 5) | j; v[j] = s[SIDX(l)]; }
    load_gate(Gall + 15 * 16, g);  gate_on32<3>(v, g);
    load_gate(Gall + 16 * 16, g);  gate_on32<2>(v, g);
    load_gate(Gall + 17 * 16, g);  gate_on32<1>(v, g);
    load_gate(Gall + 18 * 16, g);  gate_on32<0>(v, g);
    size_t off = ((size_t)b << 20) + ((size_t)chunk << 13) + ((size_t)t << 5);
#pragma unroll
    for (int p = 0; p < 4; ++p) {
        unsigned short rr[8], ri[8];
#pragma unroll
        for (int i = 0; i < 8; ++i) {
            rr[i] = f2bf(v[8 * p + i].x);
            ri[i] = f2bf(v[8 * p + i].y);
        }
        *reinterpret_cast<float4*>(Brt + off + 8 * p) = *reinterpret_cast<float4*>(rr);
        *reinterpret_cast<float4*>(Bit + off + 8 * p) = *reinterpret_cast<float4*>(ri);
    }
}

// bf16 transpose: B[t][a] -> A[a][t] for both planes, merged as u32 in LDS.
__global__ __launch_bounds__(256) void bt_t(const unsigned short* __restrict__ Brt,
                                            const unsigned short* __restrict__ Bit,
                                            unsigned short* __restrict__ Art,
                                            unsigned short* __restrict__ Ait) {
    __shared__ unsigned lds32[64 * 66];
    int b  = blockIdx.z;
    int t0 = blockIdx.x * 64;
    int a0 = blockIdx.y * 64;
    size_t gb = (size_t)b << 20;
#pragma unroll
    for (int h = 0; h < 2; ++h) {
        int p = threadIdx.x + h * 256;
        int r = p >> 3, cq = p & 7;
        size_t src = gb + (size_t)(t0 + r) * 1024 + a0 + cq * 8;
        float4 fr = *reinterpret_cast<const float4*>(Brt + src);
        float4 fi = *reinterpret_cast<const float4*>(Bit + src);
        const unsigned short* ur = reinterpret_cast<const unsigned short*>(&fr);
        const unsigned short* ui = reinterpret_cast<const unsigned short*>(&fi);
#pragma unroll
        for (int i = 0; i < 8; ++i)
            lds32[r * 66 + cq * 8 + i] = (unsigned)ur[i] | ((unsigned)ui[i] << 16);
    }
    __syncthreads();
#pragma unroll
    for (int h = 0; h < 2; ++h) {
        int q = threadIdx.x + h * 256;
        int a = q >> 3, tq = q & 7;
        unsigned short rr[8], ri[8];
#pragma unroll
        for (int i = 0; i < 8; ++i) {
            unsigned w = lds32[(tq * 8 + i) * 66 + a];
            rr[i] = (unsigned short)(w & 0xFFFF);
            ri[i] = (unsigned short)(w >> 16);
        }
        size_t dst = gb + (size_t)(a0 + a) * 1024 + t0 + tq * 8;
        *reinterpret_cast<float4*>(Art + dst) = *reinterpret_cast<float4*>(rr);
        *reinterpret_cast<float4*>(Ait + dst) = *reinterpret_cast<float4*>(ri);
    }
}

// gram_mfma5: 128x128 tiles (36 upper-tri per batch, 144 blocks), 8 waves as 4x2
// (wave-tile 32 rows x 64 cols, FULL K), dbuf 2x64KB, counted-vmcnt raw barriers.
// Per wave per K-step: 64 MFMA vs 12 ds_read + 8 gll -> compute-dense.
__global__ __launch_bounds__(512) void gram_mfma5(const unsigned short* __restrict__ Art,
                                                  const unsigned short* __restrict__ Ait,
                                                  float2* __restrict__ out) {
    __shared__ __align__(16) unsigned short lds[2][4][8192];   // 128 KB: bufs x {aR,aI,cR,cI}[128][64]
    int hw = blockIdx.x;
    int virt = (hw & 7) * 18 + (hw >> 3);        // bijective: 144 = 8*18, XCD-chunked
    int b = virt / 36;
    int rem = virt - b * 36;                     // triangular decode over 8x8, ia <= ic
    int ia = 0;
    while (rem >= 8 - ia) { rem -= 8 - ia; ++ia; }
    int ic = ia + rem;
    int a0 = ia * 128, c0 = ic * 128;
    int tid = threadIdx.x;
    int lane = tid & 63, w = tid >> 6;           // 8 waves
    int wm = w & 3, wn = w >> 2;                 // wave-tile: rows wm*32, cols wn*64
    // staging role: array = w>>1 (0..3 = aR,aI,cR,cI), row-half = w&1
    int arr = w >> 1, half = w & 1;
    const unsigned short* sp = (arr & 1) ? Ait : Art;
    int prow = (arr < 2) ? a0 : c0;
    int srow = lane >> 3, sslot = lane & 7;
    size_t gb = (size_t)b << 20;

    f32x4 accRe[2][4], accIm[2][4];
#pragma unroll
    for (int m = 0; m < 2; m++)
#pragma unroll
        for (int n = 0; n < 4; n++) { accRe[m][n] = (f32x4)0.f; accIm[m][n] = (f32x4)0.f; }

#define STAGE5(KT, BUF)                                                                   \
    {                                                                                     \
        _Pragma("unroll")                                                                 \
        for (int i = 0; i < 8; ++i) {                                                     \
            int r = (half << 6) | (i << 3) | srow;                                        \
            int sl = sslot ^ srow;                                                        \
            const unsigned short* gp = sp + gb + ((size_t)(prow + r) << 10) + (KT) * 64 + sl * 8; \
            gll16(gp, &lds[BUF][arr][((half << 6) | (i << 3)) * 64 + lane * 8]);          \
        }                                                                                 \
    }

    STAGE5(0, 0);
    for (int kt = 0; kt < 16; ++kt) {
        int cur = kt & 1;
        if (kt < 15) {
            STAGE5(kt + 1, cur ^ 1);
            asm volatile("s_waitcnt vmcnt(8)" ::: "memory");   // kt's 8 loads retired
        } else {
            asm volatile("s_waitcnt vmcnt(0)" ::: "memory");
        }
        __builtin_amdgcn_s_barrier();                          // all panels of buf[cur] landed
        __builtin_amdgcn_sched_barrier(0);
#pragma unroll
        for (int kk = 0; kk < 2; ++kk) {
            int sbase = kk * 4 + (lane >> 4);    // 16B-slot index 0..7
            short8 am[2][2], bn[4][2];
#pragma unroll
            for (int m = 0; m < 2; m++) {
                int r = wm * 32 + m * 16 + (lane & 15);
                int off = r * 64 + ((sbase ^ (r & 7)) << 3);
                am[m][0] = *reinterpret_cast<const short8*>(&lds[cur][0][off]);
                am[m][1] = *reinterpret_cast<const short8*>(&lds[cur][1][off]);
            }
#pragma unroll
            for (int n = 0; n < 4; n++) {
                int r = wn * 64 + n * 16 + (lane & 15);
                int off = r * 64 + ((sbase ^ (r & 7)) << 3);
                bn[n][0] = *reinterpret_cast<const short8*>(&lds[cur][2][off]);
                bn[n][1] = *reinterpret_cast<const short8*>(&lds[cur][3][off]);
            }
#pragma unroll
            for (int m = 0; m < 2; m++) {
                u32x4 tn = *reinterpret_cast<u32x4*>(&am[m][0]) ^ 0x80008000u;
                short8 arn = *reinterpret_cast<short8*>(&tn);
#pragma unroll
                for (int n = 0; n < 4; n++) {
                    accRe[m][n] = __builtin_amdgcn_mfma_f32_16x16x32_bf16(am[m][0], bn[n][0], accRe[m][n], 0, 0, 0);
                    accRe[m][n] = __builtin_amdgcn_mfma_f32_16x16x32_bf16(am[m][1], bn[n][1], accRe[m][n], 0, 0, 0);
                    accIm[m][n] = __builtin_amdgcn_mfma_f32_16x16x32_bf16(am[m][1], bn[n][0], accIm[m][n], 0, 0, 0);
                    accIm[m][n] = __builtin_amdgcn_mfma_f32_16x16x32_bf16(arn,      bn[n][1], accIm[m][n], 0, 0, 0);
                }
            }
        }
        asm volatile("s_waitcnt lgkmcnt(0)" ::: "memory");     // my buf[cur] reads retired
        __builtin_amdgcn_sched_barrier(0);
        __builtin_amdgcn_s_barrier();                          // safe for next kt's stage (WAR)
        __builtin_amdgcn_sched_barrier(0);
    }
#undef STAGE5
    // C/D layout: col = lane&15, row = (lane>>4)*4 + reg
    size_t ob = gb;
#pragma unroll
    for (int m = 0; m < 2; m++)
#pragma unroll
        for (int n = 0; n < 4; n++)
#pragma unroll
            for (int r = 0; r < 4; r++) {
                int a = a0 + wm * 32 + m * 16 + (lane >> 4) * 4 + r;
                int c = c0 + wn * 64 + n * 16 + (lane & 15);
                float re = accRe[m][n][r];
                float im = accIm[m][n][r];
                out[ob + ((size_t)a << 10) + c] = make_float2(re, im);
                if (ia != ic)
                    out[ob + ((size_t)c << 10) + a] = make_float2(re, -im);
            }
}

extern "C" void kernel_launch(void* const* d_in, const int* in_sizes, int n_in,
                              void* d_out, int out_size, void* d_ws, size_t ws_size,
                              hipStream_t stream) {
    const float* x = (const float*)d_in[0];
    const float* weight = (const float*)d_in[1];
    const size_t psiBytes = (size_t)BATCH * DIM * sizeof(c32);       // 32 MB
    c32* psi = (c32*)d_ws;
    c32* G = (c32*)((char*)d_ws + psiBytes);
    unsigned short* Brt = (unsigned short*)((char*)d_ws + psiBytes + 65536);
    unsigned short* Bit = Brt + (size_t)BATCH * DIM;
    unsigned short* Art = Bit + (size_t)BATCH * DIM;
    unsigned short* Ait = Art + (size_t)BATCH * DIM;

    build_gates<<<1, 64, 0, stream>>>(weight, G);
    pass_a2<<<BATCH * 128, 256, 0, stream>>>(x, psi, G);            // gates 0..6
    pass_b2<<<BATCH * 128, 256, 0, stream>>>(psi, Brt, Bit, G);     // gates 7..18 -> bf16 [t][a]
    bt_t<<<dim3(16, 16, BATCH), 256, 0, stream>>>(Brt, Bit, Art, Ait);
    gram_mfma5<<<144, 512, 0, stream>>>(Art, Ait, (float2*)d_out);
}

// Round 9
// 101.250 us; speedup vs baseline: 1.0650x; 1.0521x over previous
//
#include <hip/hip_runtime.h>
#include <hip/hip_bf16.h>

#define N_Q    20
#define DIM    (1 << N_Q)      // 1048576
#define BATCH  4
#define NGATES 19
#define L2OFF  117             // 6n-3 : second xyz layer offset

typedef float2 c32;
typedef __attribute__((ext_vector_type(8))) short short8;
typedef __attribute__((ext_vector_type(4))) float f32x4;
typedef __attribute__((ext_vector_type(4))) unsigned int u32x4;

__device__ __forceinline__ c32 cmul(c32 a, c32 b) {
    return make_float2(fmaf(a.x, b.x, -a.y * b.y), fmaf(a.x, b.y, a.y * b.x));
}
__device__ __forceinline__ c32 cmadd(c32 acc, c32 a, c32 b) {
    acc.x = fmaf(a.x, b.x, fmaf(-a.y, b.y, acc.x));
    acc.y = fmaf(a.x, b.y, fmaf(a.y, b.x, acc.y));
    return acc;
}
__device__ __forceinline__ unsigned short f2bf(float f) {
    union { float f; unsigned u; } v; v.f = f;
    unsigned r = v.u + 0x7FFFu + ((v.u >> 16) & 1u);
    return (unsigned short)(r >> 16);
}
__device__ __forceinline__ void gll16(const void* g, void* l) {
    __builtin_amdgcn_global_load_lds((const __attribute__((address_space(1))) void*)g,
                                     (__attribute__((address_space(3))) void*)l, 16, 0, 0);
}

__device__ void mm2(const c32 A[2][2], const c32 B[2][2], c32 C[2][2]) {
    for (int i = 0; i < 2; i++)
        for (int j = 0; j < 2; j++) {
            c32 s = make_float2(0.f, 0.f);
            for (int k = 0; k < 2; k++) s = cmadd(s, A[i][k], B[k][j]);
            C[i][j] = s;
        }
}
__device__ void mm4(const c32 A[4][4], const c32 B[4][4], c32 C[4][4]) {
    for (int i = 0; i < 4; i++)
        for (int j = 0; j < 4; j++) {
            c32 s = make_float2(0.f, 0.f);
            for (int k = 0; k < 4; k++) s = cmadd(s, A[i][k], B[k][j]);
            C[i][j] = s;
        }
}
__device__ void single_u(const float* w, int base, c32 U[2][2]) {
    const float WM = 0.63245553203367586640f;  // sqrt(2/5)
    float hx = w[base] * WM * 0.5f, hy = w[base + 1] * WM * 0.5f, hz = w[base + 2] * WM * 0.5f;
    float cx = cosf(hx), sx = sinf(hx);
    float cy = cosf(hy), sy = sinf(hy);
    float cz = cosf(hz), sz = sinf(hz);
    c32 RX[2][2] = {{{cx, 0.f}, {0.f, -sx}}, {{0.f, -sx}, {cx, 0.f}}};
    c32 RY[2][2] = {{{cy, 0.f}, {-sy, 0.f}}, {{sy, 0.f}, {cy, 0.f}}};
    c32 RZ[2][2] = {{{cz, -sz}, {0.f, 0.f}}, {{0.f, 0.f}, {cz, sz}}};
    c32 T[2][2];
    mm2(RY, RX, T);
    mm2(RZ, T, U);
}
__device__ void kron22(const c32 A[2][2], const c32 B[2][2], c32 K[4][4]) {
    for (int i = 0; i < 2; i++)
        for (int j = 0; j < 2; j++)
            for (int k = 0; k < 2; k++)
                for (int l = 0; l < 2; l++)
                    K[i * 2 + j][k * 2 + l] = cmul(A[i][k], B[j][l]);
}

// Build the 19 fused 4x4 staircase gates (round-0 derivation).
__global__ void build_gates(const float* __restrict__ w, c32* __restrict__ G) {
    int q = threadIdx.x;
    if (q >= NGATES) return;
    const float WM = 0.63245553203367586640f;
    float hx = w[60 + 3 * q] * WM * 0.5f;
    float hy = w[61 + 3 * q] * WM * 0.5f;
    float hz = w[62 + 3 * q] * WM * 0.5f;
    float cx = cosf(hx), sx = sinf(hx);
    float cy = cosf(hy), sy = sinf(hy);
    float cz = cosf(hz), sz = sinf(hz);
    c32 RXX[4][4], RYY[4][4], RZZ[4][4];
    for (int i = 0; i < 4; i++)
        for (int j = 0; j < 4; j++) {
            RXX[i][j] = make_float2(0.f, 0.f);
            RYY[i][j] = make_float2(0.f, 0.f);
            RZZ[i][j] = make_float2(0.f, 0.f);
        }
    for (int i = 0; i < 4; i++) {
        RXX[i][i]     = make_float2(cx, 0.f);
        RXX[i][3 - i] = make_float2(0.f, -sx);
        RYY[i][i]     = make_float2(cy, 0.f);
    }
    RYY[0][3] = make_float2(0.f,  sy);
    RYY[1][2] = make_float2(0.f, -sy);
    RYY[2][1] = make_float2(0.f, -sy);
    RYY[3][0] = make_float2(0.f,  sy);
    RZZ[0][0] = make_float2(cz, -sz);
    RZZ[1][1] = make_float2(cz,  sz);
    RZZ[2][2] = make_float2(cz,  sz);
    RZZ[3][3] = make_float2(cz, -sz);
    c32 T[4][4], M[4][4];
    mm4(RYY, RXX, T);
    mm4(RZZ, T, M);

    c32 I2m[2][2] = {{{1.f, 0.f}, {0.f, 0.f}}, {{0.f, 0.f}, {1.f, 0.f}}};
    c32 Ua[2][2], Ub[2][2], Pre[4][4], Post[4][4];
    if (q == 0) {
        single_u(w, 0, Ua);
        single_u(w, 3, Ub);
        kron22(Ua, Ub, Pre);
    } else {
        single_u(w, 3 * (q + 1), Ub);
        kron22(I2m, Ub, Pre);
    }
    if (q == NGATES - 1) {
        single_u(w, L2OFF + 3 * 18, Ua);
        single_u(w, L2OFF + 3 * 19, Ub);
        kron22(Ua, Ub, Post);
    } else {
        single_u(w, L2OFF + 3 * q, Ua);
        kron22(Ua, I2m, Post);
    }
    c32 T2[4][4], Gq[4][4];
    mm4(M, Pre, T2);
    mm4(Post, T2, Gq);
    for (int i = 0; i < 4; i++)
        for (int j = 0; j < 4; j++)
            G[q * 16 + i * 4 + j] = Gq[i][j];
}

__device__ __forceinline__ void apply4(const c32* g, c32& x0, c32& x1, c32& x2, c32& x3) {
    c32 r0 = cmul(g[0],  x0); r0 = cmadd(r0, g[1],  x1); r0 = cmadd(r0, g[2],  x2); r0 = cmadd(r0, g[3],  x3);
    c32 r1 = cmul(g[4],  x0); r1 = cmadd(r1, g[5],  x1); r1 = cmadd(r1, g[6],  x2); r1 = cmadd(r1, g[7],  x3);
    c32 r2 = cmul(g[8],  x0); r2 = cmadd(r2, g[9],  x1); r2 = cmadd(r2, g[10], x2); r2 = cmadd(r2, g[11], x3);
    c32 r3 = cmul(g[12], x0); r3 = cmadd(r3, g[13], x1); r3 = cmadd(r3, g[14], x2); r3 = cmadd(r3, g[15], x3);
    x0 = r0; x1 = r1; x2 = r2; x3 = r3;
}
__device__ __forceinline__ void load_gate(const c32* __restrict__ gp, c32 g[16]) {
#pragma unroll
    for (int k = 0; k < 16; k++) g[k] = gp[k];
}
template <int LO>
__device__ __forceinline__ void gate_on32(c32 v[32], const c32 g[16]) {
#pragma unroll
    for (int m = 0; m < 8; ++m) {
        const int j0 = ((m >> LO) << (LO + 2)) | (m & ((1 << LO) - 1));
        const int s = 1 << LO;
        apply4(g, v[j0], v[j0 + s], v[j0 + 2 * s], v[j0 + 3 * s]);
    }
}
template <int LO>
__device__ __forceinline__ void gate_on16(c32* v, const c32 g[16]) {
#pragma unroll
    for (int m = 0; m < 4; ++m) {
        const int j0 = ((m >> LO) << (LO + 2)) | (m & ((1 << LO) - 1));
        const int s = 1 << LO;
        apply4(g, v[j0], v[j0 + s], v[j0 + 2 * s], v[j0 + 3 * s]);
    }
}

// XOR swizzle for 8192-c32 LDS exchanges (verified <=4-way for all patterns used).
#define SIDX(l) ((l) ^ ((((l) >> 5) & 15)))

// Pass A2: gates 0..6 (psi bits 19..12). State = [256 rows = bits 19..12][4096 cols].
__global__ __launch_bounds__(256) void pass_a2(const float* __restrict__ x,
                                               c32* __restrict__ psi,
                                               const c32* __restrict__ Gall) {
    __shared__ __align__(16) char smem[65536];
    float* xs = (float*)smem;        // [256][32] f32, 16B-slot swizzled (32 KB)
    c32* s = (c32*)smem;             // 8192 c32 exchange view (64 KB)
    int b = blockIdx.x >> 7;
    int c0 = (blockIdx.x & 127) << 5;
    const float* xp = x + ((size_t)b << 20) + c0;
    c32* pp = psi + ((size_t)b << 20) + c0;
    int t = threadIdx.x;
#pragma unroll
    for (int i = 0; i < 8; ++i) {
        int f4 = t + (i << 8);
        int row = f4 >> 3, sl = f4 & 7;
        float4 v = *reinterpret_cast<const float4*>(xp + (size_t)row * 4096 + sl * 4);
        reinterpret_cast<float4*>(xs)[row * 8 + (sl ^ (row & 7))] = v;
    }
    __syncthreads();
    int col = t & 31, rlow = t >> 5;
    c32 v[32], g[16];
#pragma unroll
    for (int j = 0; j < 32; ++j) {
        int row = (j << 3) | rlow;
        float re = xs[row * 32 + ((((col >> 2) ^ (row & 7)) << 2) | (col & 3))];
        v[j] = make_float2(re, 0.f);
    }
    __syncthreads();
    load_gate(Gall + 0 * 16, g);  gate_on32<3>(v, g);
    load_gate(Gall + 1 * 16, g);  gate_on32<2>(v, g);
    load_gate(Gall + 2 * 16, g);  gate_on32<1>(v, g);
    load_gate(Gall + 3 * 16, g);  gate_on32<0>(v, g);
#pragma unroll
    for (int j = 0; j < 32; ++j) {
        int l = ((((j << 3) | rlow) << 5)) | col;
        s[SIDX(l)] = v[j];
    }
    __syncthreads();
    int rhi = t >> 5;
#pragma unroll
    for (int rtop = 0; rtop < 2; ++rtop)
#pragma unroll
        for (int j = 0; j < 16; ++j) {
            int row = (rtop << 7) | (rhi << 4) | j;
            int l = (row << 5) | col;
            v[rtop * 16 + j] = s[SIDX(l)];
        }
    load_gate(Gall + 4 * 16, g);  gate_on16<2>(v, g);  gate_on16<2>(v + 16, g);
    load_gate(Gall + 5 * 16, g);  gate_on16<1>(v, g);  gate_on16<1>(v + 16, g);
    load_gate(Gall + 6 * 16, g);  gate_on16<0>(v, g);  gate_on16<0>(v + 16, g);
#pragma unroll
    for (int rtop = 0; rtop < 2; ++rtop)
#pragma unroll
        for (int j = 0; j < 16; ++j) {
            int row = (rtop << 7) | (rhi << 4) | j;
            pp[(size_t)row * 4096 + col] = v[rtop * 16 + j];
        }
}

// Pass B2: gates 7..18 (psi bits 12..0). 3 register phases, 2 LDS exchanges;
// writes planar bf16 [t][a] (Brt, Bit).
__global__ __launch_bounds__(256) void pass_b2(const c32* __restrict__ psi,
                                               unsigned short* __restrict__ Brt,
                                               unsigned short* __restrict__ Bit,
                                               const c32* __restrict__ Gall) {
    __shared__ c32 s[8192];
    int b = blockIdx.x >> 7;
    int chunk = blockIdx.x & 127;
    const c32* pp = psi + ((size_t)b << 20) + ((size_t)chunk << 13);
    int t = threadIdx.x;
    c32 v[32], g[16];
#pragma unroll
    for (int j = 0; j < 32; ++j) v[j] = pp[(j << 8) | t];
    load_gate(Gall + 7 * 16, g);   gate_on32<3>(v, g);
    load_gate(Gall + 8 * 16, g);   gate_on32<2>(v, g);
    load_gate(Gall + 9 * 16, g);   gate_on32<1>(v, g);
    load_gate(Gall + 10 * 16, g);  gate_on32<0>(v, g);
#pragma unroll
    for (int j = 0; j < 32; ++j) { int l = (j << 8) | t; s[SIDX(l)] = v[j]; }
    __syncthreads();
    int hi2 = (t >> 4) << 9, lo2 = t & 15;
#pragma unroll
    for (int j = 0; j < 32; ++j) { int l = hi2 | (j << 4) | lo2; v[j] = s[SIDX(l)]; }
    load_gate(Gall + 11 * 16, g);  gate_on32<3>(v, g);
    load_gate(Gall + 12 * 16, g);  gate_on32<2>(v, g);
    load_gate(Gall + 13 * 16, g);  gate_on32<1>(v, g);
    load_gate(Gall + 14 * 16, g);  gate_on32<0>(v, g);
    __syncthreads();
#pragma unroll
    for (int j = 0; j < 32; ++j) { int l = hi2 | (j << 4) | lo2; s[SIDX(l)] = v[j]; }
    __syncthreads();
#pragma unroll
    for (int j = 0; j < 32; ++j) { int l = (t << 5) | j; v[j] = s[SIDX(l)]; }
    load_gate(Gall + 15 * 16, g);  gate_on32<3>(v, g);
    load_gate(Gall + 16 * 16, g);  gate_on32<2>(v, g);
    load_gate(Gall + 17 * 16, g);  gate_on32<1>(v, g);
    load_gate(Gall + 18 * 16, g);  gate_on32<0>(v, g);
    size_t off = ((size_t)b << 20) + ((size_t)chunk << 13) + ((size_t)t << 5);
#pragma unroll
    for (int p = 0; p < 4; ++p) {
        unsigned short rr[8], ri[8];
#pragma unroll
        for (int i = 0; i < 8; ++i) {
            rr[i] = f2bf(v[8 * p + i].x);
            ri[i] = f2bf(v[8 * p + i].y);
        }
        *reinterpret_cast<float4*>(Brt + off + 8 * p) = *reinterpret_cast<float4*>(rr);
        *reinterpret_cast<float4*>(Bit + off + 8 * p) = *reinterpret_cast<float4*>(ri);
    }
}

// bf16 transpose: B[t][a] -> A[a][t] for both planes, merged as u32 in LDS.
__global__ __launch_bounds__(256) void bt_t(const unsigned short* __restrict__ Brt,
                                            const unsigned short* __restrict__ Bit,
                                            unsigned short* __restrict__ Art,
                                            unsigned short* __restrict__ Ait) {
    __shared__ unsigned lds32[64 * 66];
    int b  = blockIdx.z;
    int t0 = blockIdx.x * 64;
    int a0 = blockIdx.y * 64;
    size_t gb = (size_t)b << 20;
#pragma unroll
    for (int h = 0; h < 2; ++h) {
        int p = threadIdx.x + h * 256;
        int r = p >> 3, cq = p & 7;
        size_t src = gb + (size_t)(t0 + r) * 1024 + a0 + cq * 8;
        float4 fr = *reinterpret_cast<const float4*>(Brt + src);
        float4 fi = *reinterpret_cast<const float4*>(Bit + src);
        const unsigned short* ur = reinterpret_cast<const unsigned short*>(&fr);
        const unsigned short* ui = reinterpret_cast<const unsigned short*>(&fi);
#pragma unroll
        for (int i = 0; i < 8; ++i)
            lds32[r * 66 + cq * 8 + i] = (unsigned)ur[i] | ((unsigned)ui[i] << 16);
    }
    __syncthreads();
#pragma unroll
    for (int h = 0; h < 2; ++h) {
        int q = threadIdx.x + h * 256;
        int a = q >> 3, tq = q & 7;
        unsigned short rr[8], ri[8];
#pragma unroll
        for (int i = 0; i < 8; ++i) {
            unsigned w = lds32[(tq * 8 + i) * 66 + a];
            rr[i] = (unsigned short)(w & 0xFFFF);
            ri[i] = (unsigned short)(w >> 16);
        }
        size_t dst = gb + (size_t)(a0 + a) * 1024 + t0 + tq * 8;
        *reinterpret_cast<float4*>(Art + dst) = *reinterpret_cast<float4*>(rr);
        *reinterpret_cast<float4*>(Ait + dst) = *reinterpret_cast<float4*>(ri);
    }
}

// gram_mfma5b: K-loop IDENTICAL to round 8. Epilogue changed: the mirror tile is
// no longer written with an 8KB-stride 8B scatter (the suspected 42us pin);
// instead it is conjugate-transposed through the (now dead) staging LDS and
// streamed out with fully coalesced 1KB rows.
__global__ __launch_bounds__(512) void gram_mfma5b(const unsigned short* __restrict__ Art,
                                                   const unsigned short* __restrict__ Ait,
                                                   float2* __restrict__ out) {
    __shared__ __align__(16) unsigned short lds[2][4][8192];   // 128 KB: bufs x {aR,aI,cR,cI}[128][64]
    int hw = blockIdx.x;
    int virt = (hw & 7) * 18 + (hw >> 3);        // bijective: 144 = 8*18, XCD-chunked
    int b = virt / 36;
    int rem = virt - b * 36;                     // triangular decode over 8x8, ia <= ic
    int ia = 0;
    while (rem >= 8 - ia) { rem -= 8 - ia; ++ia; }
    int ic = ia + rem;
    int a0 = ia * 128, c0 = ic * 128;
    int tid = threadIdx.x;
    int lane = tid & 63, w = tid >> 6;           // 8 waves
    int wm = w & 3, wn = w >> 2;                 // wave-tile: rows wm*32, cols wn*64
    int arr = w >> 1, half = w & 1;
    const unsigned short* sp = (arr & 1) ? Ait : Art;
    int prow = (arr < 2) ? a0 : c0;
    int srow = lane >> 3, sslot = lane & 7;
    size_t gb = (size_t)b << 20;

    f32x4 accRe[2][4], accIm[2][4];
#pragma unroll
    for (int m = 0; m < 2; m++)
#pragma unroll
        for (int n = 0; n < 4; n++) { accRe[m][n] = (f32x4)0.f; accIm[m][n] = (f32x4)0.f; }

#define STAGE5(KT, BUF)                                                                   \
    {                                                                                     \
        _Pragma("unroll")                                                                 \
        for (int i = 0; i < 8; ++i) {                                                     \
            int r = (half << 6) | (i << 3) | srow;                                        \
            int sl = sslot ^ srow;                                                        \
            const unsigned short* gp = sp + gb + ((size_t)(prow + r) << 10) + (KT) * 64 + sl * 8; \
            gll16(gp, &lds[BUF][arr][((half << 6) | (i << 3)) * 64 + lane * 8]);          \
        }                                                                                 \
    }

    STAGE5(0, 0);
    for (int kt = 0; kt < 16; ++kt) {
        int cur = kt & 1;
        if (kt < 15) {
            STAGE5(kt + 1, cur ^ 1);
            asm volatile("s_waitcnt vmcnt(8)" ::: "memory");   // kt's 8 loads retired
        } else {
            asm volatile("s_waitcnt vmcnt(0)" ::: "memory");
        }
        __builtin_amdgcn_s_barrier();                          // all panels of buf[cur] landed
        __builtin_amdgcn_sched_barrier(0);
#pragma unroll
        for (int kk = 0; kk < 2; ++kk) {
            int sbase = kk * 4 + (lane >> 4);    // 16B-slot index 0..7
            short8 am[2][2], bn[4][2];
#pragma unroll
            for (int m = 0; m < 2; m++) {
                int r = wm * 32 + m * 16 + (lane & 15);
                int off = r * 64 + ((sbase ^ (r & 7)) << 3);
                am[m][0] = *reinterpret_cast<const short8*>(&lds[cur][0][off]);
                am[m][1] = *reinterpret_cast<const short8*>(&lds[cur][1][off]);
            }
#pragma unroll
            for (int n = 0; n < 4; n++) {
                int r = wn * 64 + n * 16 + (lane & 15);
                int off = r * 64 + ((sbase ^ (r & 7)) << 3);
                bn[n][0] = *reinterpret_cast<const short8*>(&lds[cur][2][off]);
                bn[n][1] = *reinterpret_cast<const short8*>(&lds[cur][3][off]);
            }
#pragma unroll
            for (int m = 0; m < 2; m++) {
                u32x4 tn = *reinterpret_cast<u32x4*>(&am[m][0]) ^ 0x80008000u;
                short8 arn = *reinterpret_cast<short8*>(&tn);
#pragma unroll
                for (int n = 0; n < 4; n++) {
                    accRe[m][n] = __builtin_amdgcn_mfma_f32_16x16x32_bf16(am[m][0], bn[n][0], accRe[m][n], 0, 0, 0);
                    accRe[m][n] = __builtin_amdgcn_mfma_f32_16x16x32_bf16(am[m][1], bn[n][1], accRe[m][n], 0, 0, 0);
                    accIm[m][n] = __builtin_amdgcn_mfma_f32_16x16x32_bf16(am[m][1], bn[n][0], accIm[m][n], 0, 0, 0);
                    accIm[m][n] = __builtin_amdgcn_mfma_f32_16x16x32_bf16(arn,      bn[n][1], accIm[m][n], 0, 0, 0);
                }
            }
        }
        asm volatile("s_waitcnt lgkmcnt(0)" ::: "memory");     // my buf[cur] reads retired
        __builtin_amdgcn_sched_barrier(0);
        __builtin_amdgcn_s_barrier();                          // safe for next kt's stage (WAR)
        __builtin_amdgcn_sched_barrier(0);
    }
#undef STAGE5
    // ---- epilogue ----
    // Direct (upper) tile: 128B-segment stores, as before.
    // C/D layout: col = lane&15, row = (lane>>4)*4 + reg
    size_t ob = gb;
#pragma unroll
    for (int m = 0; m < 2; m++)
#pragma unroll
        for (int n = 0; n < 4; n++)
#pragma unroll
            for (int r = 0; r < 4; r++) {
                int a = a0 + wm * 32 + m * 16 + (lane >> 4) * 4 + r;
                int c = c0 + wn * 64 + n * 16 + (lane & 15);
                out[ob + ((size_t)a << 10) + c] = make_float2(accRe[m][n][r], accIm[m][n][r]);
            }
    // Mirror (lower) tile via LDS conj-transpose: two 64-col halves, coalesced out.
    if (ia != ic) {
        float2* mlds = reinterpret_cast<float2*>(&lds[0][0][0]);   // [64][131] float2 = 67 KB < 128 KB
#pragma unroll
        for (int h = 0; h < 2; ++h) {
            __syncthreads();                    // K-loop LDS dead / prev-h reads done
            if (wn == h) {
#pragma unroll
                for (int m = 0; m < 2; m++)
#pragma unroll
                    for (int n = 0; n < 4; n++)
#pragma unroll
                        for (int r = 0; r < 4; r++) {
                            int a_l = wm * 32 + m * 16 + (lane >> 4) * 4 + r;   // 0..127
                            int c_l = n * 16 + (lane & 15);                     // 0..63 within half
                            mlds[c_l * 131 + a_l] = make_float2(accRe[m][n][r], -accIm[m][n][r]);
                        }
            }
            __syncthreads();
#pragma unroll
            for (int i = 0; i < 16; ++i) {
                int p = tid + (i << 9);          // 8192 float2 = [64 c-rows][128 a-cols]
                int row = p >> 7, col = p & 127;
                out[ob + ((size_t)(c0 + h * 64 + row) << 10) + a0 + col] = mlds[row * 131 + col];
            }
        }
    }
}

extern "C" void kernel_launch(void* const* d_in, const int* in_sizes, int n_in,
                              void* d_out, int out_size, void* d_ws, size_t ws_size,
                              hipStream_t stream) {
    const float* x = (const float*)d_in[0];
    const float* weight = (const float*)d_in[1];
    const size_t psiBytes = (size_t)BATCH * DIM * sizeof(c32);       // 32 MB
    c32* psi = (c32*)d_ws;
    c32* G = (c32*)((char*)d_ws + psiBytes);
    unsigned short* Brt = (unsigned short*)((char*)d_ws + psiBytes + 65536);
    unsigned short* Bit = Brt + (size_t)BATCH * DIM;
    unsigned short* Art = Bit + (size_t)BATCH * DIM;
    unsigned short* Ait = Art + (size_t)BATCH * DIM;

    build_gates<<<1, 64, 0, stream>>>(weight, G);
    pass_a2<<<BATCH * 128, 256, 0, stream>>>(x, psi, G);            // gates 0..6
    pass_b2<<<BATCH * 128, 256, 0, stream>>>(psi, Brt, Bit, G);     // gates 7..18 -> bf16 [t][a]
    bt_t<<<dim3(16, 16, BATCH), 256, 0, stream>>>(Brt, Bit, Art, Ait);
    gram_mfma5b<<<144, 512, 0, stream>>>(Art, Ait, (float2*)d_out);
}

// Round 10
// 101.149 us; speedup vs baseline: 1.0661x; 1.0010x over previous
//
#include <hip/hip_runtime.h>
#include <hip/hip_bf16.h>

#define N_Q    20
#define DIM    (1 << N_Q)      // 1048576
#define BATCH  4
#define NGATES 19
#define L2OFF  117             // 6n-3 : second xyz layer offset
#define GSTRIDE 32             // per-gate: 16 g + 16 gs(swapped-negated)

typedef float2 c32;
typedef __attribute__((ext_vector_type(2))) float fv2;
typedef __attribute__((ext_vector_type(8))) short short8;
typedef __attribute__((ext_vector_type(4))) float f32x4;
typedef __attribute__((ext_vector_type(4))) unsigned int u32x4;

__device__ __forceinline__ c32 cmul(c32 a, c32 b) {
    return make_float2(fmaf(a.x, b.x, -a.y * b.y), fmaf(a.x, b.y, a.y * b.x));
}
__device__ __forceinline__ c32 cmadd(c32 acc, c32 a, c32 b) {
    acc.x = fmaf(a.x, b.x, fmaf(-a.y, b.y, acc.x));
    acc.y = fmaf(a.x, b.y, fmaf(a.y, b.x, acc.y));
    return acc;
}
__device__ __forceinline__ unsigned short f2bf(float f) {
    union { float f; unsigned u; } v; v.f = f;
    unsigned r = v.u + 0x7FFFu + ((v.u >> 16) & 1u);
    return (unsigned short)(r >> 16);
}
__device__ __forceinline__ void gll16(const void* g, void* l) {
    __builtin_amdgcn_global_load_lds((const __attribute__((address_space(1))) void*)g,
                                     (__attribute__((address_space(3))) void*)l, 16, 0, 0);
}

__device__ void mm2(const c32 A[2][2], const c32 B[2][2], c32 C[2][2]) {
    for (int i = 0; i < 2; i++)
        for (int j = 0; j < 2; j++) {
            c32 s = make_float2(0.f, 0.f);
            for (int k = 0; k < 2; k++) s = cmadd(s, A[i][k], B[k][j]);
            C[i][j] = s;
        }
}
__device__ void mm4(const c32 A[4][4], const c32 B[4][4], c32 C[4][4]) {
    for (int i = 0; i < 4; i++)
        for (int j = 0; j < 4; j++) {
            c32 s = make_float2(0.f, 0.f);
            for (int k = 0; k < 4; k++) s = cmadd(s, A[i][k], B[k][j]);
            C[i][j] = s;
        }
}
__device__ void single_u(const float* w, int base, c32 U[2][2]) {
    const float WM = 0.63245553203367586640f;  // sqrt(2/5)
    float hx = w[base] * WM * 0.5f, hy = w[base + 1] * WM * 0.5f, hz = w[base + 2] * WM * 0.5f;
    float cx = cosf(hx), sx = sinf(hx);
    float cy = cosf(hy), sy = sinf(hy);
    float cz = cosf(hz), sz = sinf(hz);
    c32 RX[2][2] = {{{cx, 0.f}, {0.f, -sx}}, {{0.f, -sx}, {cx, 0.f}}};
    c32 RY[2][2] = {{{cy, 0.f}, {-sy, 0.f}}, {{sy, 0.f}, {cy, 0.f}}};
    c32 RZ[2][2] = {{{cz, -sz}, {0.f, 0.f}}, {{0.f, 0.f}, {cz, sz}}};
    c32 T[2][2];
    mm2(RY, RX, T);
    mm2(RZ, T, U);
}
__device__ void kron22(const c32 A[2][2], const c32 B[2][2], c32 K[4][4]) {
    for (int i = 0; i < 2; i++)
        for (int j = 0; j < 2; j++)
            for (int k = 0; k < 2; k++)
                for (int l = 0; l < 2; l++)
                    K[i * 2 + j][k * 2 + l] = cmul(A[i][k], B[j][l]);
}

// Build the 19 fused 4x4 staircase gates; emit both g and gs=(-g.y, g.x) tables.
__global__ void build_gates(const float* __restrict__ w, c32* __restrict__ G) {
    int q = threadIdx.x;
    if (q >= NGATES) return;
    const float WM = 0.63245553203367586640f;
    float hx = w[60 + 3 * q] * WM * 0.5f;
    float hy = w[61 + 3 * q] * WM * 0.5f;
    float hz = w[62 + 3 * q] * WM * 0.5f;
    float cx = cosf(hx), sx = sinf(hx);
    float cy = cosf(hy), sy = sinf(hy);
    float cz = cosf(hz), sz = sinf(hz);
    c32 RXX[4][4], RYY[4][4], RZZ[4][4];
    for (int i = 0; i < 4; i++)
        for (int j = 0; j < 4; j++) {
            RXX[i][j] = make_float2(0.f, 0.f);
            RYY[i][j] = make_float2(0.f, 0.f);
            RZZ[i][j] = make_float2(0.f, 0.f);
        }
    for (int i = 0; i < 4; i++) {
        RXX[i][i]     = make_float2(cx, 0.f);
        RXX[i][3 - i] = make_float2(0.f, -sx);
        RYY[i][i]     = make_float2(cy, 0.f);
    }
    RYY[0][3] = make_float2(0.f,  sy);
    RYY[1][2] = make_float2(0.f, -sy);
    RYY[2][1] = make_float2(0.f, -sy);
    RYY[3][0] = make_float2(0.f,  sy);
    RZZ[0][0] = make_float2(cz, -sz);
    RZZ[1][1] = make_float2(cz,  sz);
    RZZ[2][2] = make_float2(cz,  sz);
    RZZ[3][3] = make_float2(cz, -sz);
    c32 T[4][4], M[4][4];
    mm4(RYY, RXX, T);
    mm4(RZZ, T, M);

    c32 I2m[2][2] = {{{1.f, 0.f}, {0.f, 0.f}}, {{0.f, 0.f}, {1.f, 0.f}}};
    c32 Ua[2][2], Ub[2][2], Pre[4][4], Post[4][4];
    if (q == 0) {
        single_u(w, 0, Ua);
        single_u(w, 3, Ub);
        kron22(Ua, Ub, Pre);
    } else {
        single_u(w, 3 * (q + 1), Ub);
        kron22(I2m, Ub, Pre);
    }
    if (q == NGATES - 1) {
        single_u(w, L2OFF + 3 * 18, Ua);
        single_u(w, L2OFF + 3 * 19, Ub);
        kron22(Ua, Ub, Post);
    } else {
        single_u(w, L2OFF + 3 * q, Ua);
        kron22(Ua, I2m, Post);
    }
    c32 T2[4][4], Gq[4][4];
    mm4(M, Pre, T2);
    mm4(Post, T2, Gq);
    for (int i = 0; i < 4; i++)
        for (int j = 0; j < 4; j++) {
            c32 g = Gq[i][j];
            G[q * GSTRIDE + i * 4 + j]      = g;
            G[q * GSTRIDE + 16 + i * 4 + j] = make_float2(-g.y, g.x);
        }
}

// Packed complex 4x4 apply: r_i = sum_j x_j * g[i*4+j], complex mult as
// x.xx*g + x.yy*gs -> 2 v_pk_fma_f32 per complex MAC (vs 4 scalar fma).
__device__ __forceinline__ void apply4pk(const fv2 g[16], const fv2 gs[16],
                                         fv2& x0, fv2& x1, fv2& x2, fv2& x3) {
    fv2 a0 = (fv2)(x0[0]), b0 = (fv2)(x0[1]);
    fv2 a1 = (fv2)(x1[0]), b1 = (fv2)(x1[1]);
    fv2 a2 = (fv2)(x2[0]), b2 = (fv2)(x2[1]);
    fv2 a3 = (fv2)(x3[0]), b3 = (fv2)(x3[1]);
    fv2 r0 = a0 * g[0];  r0 += b0 * gs[0];  r0 += a1 * g[1];  r0 += b1 * gs[1];
    r0 += a2 * g[2];     r0 += b2 * gs[2];  r0 += a3 * g[3];  r0 += b3 * gs[3];
    fv2 r1 = a0 * g[4];  r1 += b0 * gs[4];  r1 += a1 * g[5];  r1 += b1 * gs[5];
    r1 += a2 * g[6];     r1 += b2 * gs[6];  r1 += a3 * g[7];  r1 += b3 * gs[7];
    fv2 r2 = a0 * g[8];  r2 += b0 * gs[8];  r2 += a1 * g[9];  r2 += b1 * gs[9];
    r2 += a2 * g[10];    r2 += b2 * gs[10]; r2 += a3 * g[11]; r2 += b3 * gs[11];
    fv2 r3 = a0 * g[12]; r3 += b0 * gs[12]; r3 += a1 * g[13]; r3 += b1 * gs[13];
    r3 += a2 * g[14];    r3 += b2 * gs[14]; r3 += a3 * g[15]; r3 += b3 * gs[15];
    x0 = r0; x1 = r1; x2 = r2; x3 = r3;
}
__device__ __forceinline__ void load_gate2(const fv2* __restrict__ gp, fv2 g[16], fv2 gs[16]) {
#pragma unroll
    for (int k = 0; k < 16; k++) { g[k] = gp[k]; gs[k] = gp[16 + k]; }
}
template <int LO>
__device__ __forceinline__ void gate_on32(fv2 v[32], const fv2 g[16], const fv2 gs[16]) {
#pragma unroll
    for (int m = 0; m < 8; ++m) {
        const int j0 = ((m >> LO) << (LO + 2)) | (m & ((1 << LO) - 1));
        const int s = 1 << LO;
        apply4pk(g, gs, v[j0], v[j0 + s], v[j0 + 2 * s], v[j0 + 3 * s]);
    }
}
template <int LO>
__device__ __forceinline__ void gate_on16(fv2* v, const fv2 g[16], const fv2 gs[16]) {
#pragma unroll
    for (int m = 0; m < 4; ++m) {
        const int j0 = ((m >> LO) << (LO + 2)) | (m & ((1 << LO) - 1));
        const int s = 1 << LO;
        apply4pk(g, gs, v[j0], v[j0 + s], v[j0 + 2 * s], v[j0 + 3 * s]);
    }
}

// XOR swizzle for 8192-elem LDS exchanges (verified <=4-way for all patterns used).
#define SIDX(l) ((l) ^ ((((l) >> 5) & 15)))

// Pass A2: gates 0..6 (psi bits 19..12). State = [256 rows = bits 19..12][4096 cols].
__global__ __launch_bounds__(256) void pass_a2(const float* __restrict__ x,
                                               c32* __restrict__ psi,
                                               const c32* __restrict__ Gall) {
    __shared__ __align__(16) char smem[65536];
    float* xs = (float*)smem;        // [256][32] f32, 16B-slot swizzled (32 KB)
    fv2* s = (fv2*)smem;             // 8192 fv2 exchange view (64 KB)
    const fv2* Gf = (const fv2*)Gall;
    int b = blockIdx.x >> 7;
    int c0 = (blockIdx.x & 127) << 5;
    const float* xp = x + ((size_t)b << 20) + c0;
    fv2* pp = (fv2*)(psi + ((size_t)b << 20) + c0);
    int t = threadIdx.x;
#pragma unroll
    for (int i = 0; i < 8; ++i) {
        int f4 = t + (i << 8);
        int row = f4 >> 3, sl = f4 & 7;
        float4 v = *reinterpret_cast<const float4*>(xp + (size_t)row * 4096 + sl * 4);
        reinterpret_cast<float4*>(xs)[row * 8 + (sl ^ (row & 7))] = v;
    }
    __syncthreads();
    int col = t & 31, rlow = t >> 5;
    fv2 v[32], g[16], gs[16];
#pragma unroll
    for (int j = 0; j < 32; ++j) {
        int row = (j << 3) | rlow;
        float re = xs[row * 32 + ((((col >> 2) ^ (row & 7)) << 2) | (col & 3))];
        v[j] = (fv2){re, 0.f};
    }
    __syncthreads();
    load_gate2(Gf + 0 * GSTRIDE, g, gs);  gate_on32<3>(v, g, gs);
    load_gate2(Gf + 1 * GSTRIDE, g, gs);  gate_on32<2>(v, g, gs);
    load_gate2(Gf + 2 * GSTRIDE, g, gs);  gate_on32<1>(v, g, gs);
    load_gate2(Gf + 3 * GSTRIDE, g, gs);  gate_on32<0>(v, g, gs);
#pragma unroll
    for (int j = 0; j < 32; ++j) {
        int l = ((((j << 3) | rlow) << 5)) | col;
        s[SIDX(l)] = v[j];
    }
    __syncthreads();
    int rhi = t >> 5;
#pragma unroll
    for (int rtop = 0; rtop < 2; ++rtop)
#pragma unroll
        for (int j = 0; j < 16; ++j) {
            int row = (rtop << 7) | (rhi << 4) | j;
            int l = (row << 5) | col;
            v[rtop * 16 + j] = s[SIDX(l)];
        }
    load_gate2(Gf + 4 * GSTRIDE, g, gs);  gate_on16<2>(v, g, gs);  gate_on16<2>(v + 16, g, gs);
    load_gate2(Gf + 5 * GSTRIDE, g, gs);  gate_on16<1>(v, g, gs);  gate_on16<1>(v + 16, g, gs);
    load_gate2(Gf + 6 * GSTRIDE, g, gs);  gate_on16<0>(v, g, gs);  gate_on16<0>(v + 16, g, gs);
#pragma unroll
    for (int rtop = 0; rtop < 2; ++rtop)
#pragma unroll
        for (int j = 0; j < 16; ++j) {
            int row = (rtop << 7) | (rhi << 4) | j;
            pp[(size_t)row * 4096 + col] = v[rtop * 16 + j];
        }
}

// Pass B2: gates 7..18 (psi bits 12..0). 3 register phases, 2 LDS exchanges;
// writes planar bf16 [t][a] (Brt, Bit).
__global__ __launch_bounds__(256) void pass_b2(const c32* __restrict__ psi,
                                               unsigned short* __restrict__ Brt,
                                               unsigned short* __restrict__ Bit,
                                               const c32* __restrict__ Gall) {
    __shared__ fv2 s[8192];
    const fv2* Gf = (const fv2*)Gall;
    int b = blockIdx.x >> 7;
    int chunk = blockIdx.x & 127;
    const fv2* pp = (const fv2*)(psi + ((size_t)b << 20) + ((size_t)chunk << 13));
    int t = threadIdx.x;
    fv2 v[32], g[16], gs[16];
#pragma unroll
    for (int j = 0; j < 32; ++j) v[j] = pp[(j << 8) | t];
    load_gate2(Gf + 7 * GSTRIDE, g, gs);   gate_on32<3>(v, g, gs);
    load_gate2(Gf + 8 * GSTRIDE, g, gs);   gate_on32<2>(v, g, gs);
    load_gate2(Gf + 9 * GSTRIDE, g, gs);   gate_on32<1>(v, g, gs);
    load_gate2(Gf + 10 * GSTRIDE, g, gs);  gate_on32<0>(v, g, gs);
#pragma unroll
    for (int j = 0; j < 32; ++j) { int l = (j << 8) | t; s[SIDX(l)] = v[j]; }
    __syncthreads();
    int hi2 = (t >> 4) << 9, lo2 = t & 15;
#pragma unroll
    for (int j = 0; j < 32; ++j) { int l = hi2 | (j << 4) | lo2; v[j] = s[SIDX(l)]; }
    load_gate2(Gf + 11 * GSTRIDE, g, gs);  gate_on32<3>(v, g, gs);
    load_gate2(Gf + 12 * GSTRIDE, g, gs);  gate_on32<2>(v, g, gs);
    load_gate2(Gf + 13 * GSTRIDE, g, gs);  gate_on32<1>(v, g, gs);
    load_gate2(Gf + 14 * GSTRIDE, g, gs);  gate_on32<0>(v, g, gs);
    __syncthreads();
#pragma unroll
    for (int j = 0; j < 32; ++j) { int l = hi2 | (j << 4) | lo2; s[SIDX(l)] = v[j]; }
    __syncthreads();
#pragma unroll
    for (int j = 0; j < 32; ++j) { int l = (t << 5) | j; v[j] = s[SIDX(l)]; }
    load_gate2(Gf + 15 * GSTRIDE, g, gs);  gate_on32<3>(v, g, gs);
    load_gate2(Gf + 16 * GSTRIDE, g, gs);  gate_on32<2>(v, g, gs);
    load_gate2(Gf + 17 * GSTRIDE, g, gs);  gate_on32<1>(v, g, gs);
    load_gate2(Gf + 18 * GSTRIDE, g, gs);  gate_on32<0>(v, g, gs);
    size_t off = ((size_t)b << 20) + ((size_t)chunk << 13) + ((size_t)t << 5);
#pragma unroll
    for (int p = 0; p < 4; ++p) {
        unsigned short rr[8], ri[8];
#pragma unroll
        for (int i = 0; i < 8; ++i) {
            rr[i] = f2bf(v[8 * p + i][0]);
            ri[i] = f2bf(v[8 * p + i][1]);
        }
        *reinterpret_cast<float4*>(Brt + off + 8 * p) = *reinterpret_cast<float4*>(rr);
        *reinterpret_cast<float4*>(Bit + off + 8 * p) = *reinterpret_cast<float4*>(ri);
    }
}

// bf16 transpose: B[t][a] -> A[a][t] for both planes, merged as u32 in LDS.
__global__ __launch_bounds__(256) void bt_t(const unsigned short* __restrict__ Brt,
                                            const unsigned short* __restrict__ Bit,
                                            unsigned short* __restrict__ Art,
                                            unsigned short* __restrict__ Ait) {
    __shared__ unsigned lds32[64 * 66];
    int b  = blockIdx.z;
    int t0 = blockIdx.x * 64;
    int a0 = blockIdx.y * 64;
    size_t gb = (size_t)b << 20;
#pragma unroll
    for (int h = 0; h < 2; ++h) {
        int p = threadIdx.x + h * 256;
        int r = p >> 3, cq = p & 7;
        size_t src = gb + (size_t)(t0 + r) * 1024 + a0 + cq * 8;
        float4 fr = *reinterpret_cast<const float4*>(Brt + src);
        float4 fi = *reinterpret_cast<const float4*>(Bit + src);
        const unsigned short* ur = reinterpret_cast<const unsigned short*>(&fr);
        const unsigned short* ui = reinterpret_cast<const unsigned short*>(&fi);
#pragma unroll
        for (int i = 0; i < 8; ++i)
            lds32[r * 66 + cq * 8 + i] = (unsigned)ur[i] | ((unsigned)ui[i] << 16);
    }
    __syncthreads();
#pragma unroll
    for (int h = 0; h < 2; ++h) {
        int q = threadIdx.x + h * 256;
        int a = q >> 3, tq = q & 7;
        unsigned short rr[8], ri[8];
#pragma unroll
        for (int i = 0; i < 8; ++i) {
            unsigned w = lds32[(tq * 8 + i) * 66 + a];
            rr[i] = (unsigned short)(w & 0xFFFF);
            ri[i] = (unsigned short)(w >> 16);
        }
        size_t dst = gb + (size_t)(a0 + a) * 1024 + t0 + tq * 8;
        *reinterpret_cast<float4*>(Art + dst) = *reinterpret_cast<float4*>(rr);
        *reinterpret_cast<float4*>(Ait + dst) = *reinterpret_cast<float4*>(ri);
    }
}

// gram_mfma5c: r9 kernel with (a) single barrier per K-step (vmcnt(0)+barrier at
// top, STAGE after barrier -- WAR-safe: readers drained lgkmcnt(0) before the
// PREVIOUS barrier; vmcnt(0) has a full compute phase of slack), (b) setprio
// around the MFMA cluster (T5), (c) coalesced LDS mirror epilogue (r9).
__global__ __launch_bounds__(512) void gram_mfma5c(const unsigned short* __restrict__ Art,
                                                   const unsigned short* __restrict__ Ait,
                                                   float2* __restrict__ out) {
    __shared__ __align__(16) unsigned short lds[2][4][8192];   // 128 KB
    int hw = blockIdx.x;
    int virt = (hw & 7) * 18 + (hw >> 3);        // bijective: 144 = 8*18, XCD-chunked
    int b = virt / 36;
    int rem = virt - b * 36;                     // triangular decode over 8x8, ia <= ic
    int ia = 0;
    while (rem >= 8 - ia) { rem -= 8 - ia; ++ia; }
    int ic = ia + rem;
    int a0 = ia * 128, c0 = ic * 128;
    int tid = threadIdx.x;
    int lane = tid & 63, w = tid >> 6;           // 8 waves
    int wm = w & 3, wn = w >> 2;                 // wave-tile: rows wm*32, cols wn*64
    int arr = w >> 1, half = w & 1;
    const unsigned short* sp = (arr & 1) ? Ait : Art;
    int prow = (arr < 2) ? a0 : c0;
    int srow = lane >> 3, sslot = lane & 7;
    size_t gb = (size_t)b << 20;

    f32x4 accRe[2][4], accIm[2][4];
#pragma unroll
    for (int m = 0; m < 2; m++)
#pragma unroll
        for (int n = 0; n < 4; n++) { accRe[m][n] = (f32x4)0.f; accIm[m][n] = (f32x4)0.f; }

#define STAGE5(KT, BUF)                                                                   \
    {                                                                                     \
        _Pragma("unroll")                                                                 \
        for (int i = 0; i < 8; ++i) {                                                     \
            int r = (half << 6) | (i << 3) | srow;                                        \
            int sl = sslot ^ srow;                                                        \
            const unsigned short* gp = sp + gb + ((size_t)(prow + r) << 10) + (KT) * 64 + sl * 8; \
            gll16(gp, &lds[BUF][arr][((half << 6) | (i << 3)) * 64 + lane * 8]);          \
        }                                                                                 \
    }

    STAGE5(0, 0);
    for (int kt = 0; kt < 16; ++kt) {
        int cur = kt & 1;
        asm volatile("s_waitcnt vmcnt(0)" ::: "memory");   // buf[cur] loads landed (slack = prev compute)
        __builtin_amdgcn_s_barrier();                      // all waves' panels in place
        __builtin_amdgcn_sched_barrier(0);
        if (kt < 15) STAGE5(kt + 1, cur ^ 1);              // safe: cur^1 readers drained before prev barrier
        __builtin_amdgcn_s_setprio(1);
#pragma unroll
        for (int kk = 0; kk < 2; ++kk) {
            int sbase = kk * 4 + (lane >> 4);    // 16B-slot index 0..7
            short8 am[2][2], bn[4][2];
#pragma unroll
            for (int m = 0; m < 2; m++) {
                int r = wm * 32 + m * 16 + (lane & 15);
                int off = r * 64 + ((sbase ^ (r & 7)) << 3);
                am[m][0] = *reinterpret_cast<const short8*>(&lds[cur][0][off]);
                am[m][1] = *reinterpret_cast<const short8*>(&lds[cur][1][off]);
            }
#pragma unroll
            for (int n = 0; n < 4; n++) {
                int r = wn * 64 + n * 16 + (lane & 15);
                int off = r * 64 + ((sbase ^ (r & 7)) << 3);
                bn[n][0] = *reinterpret_cast<const short8*>(&lds[cur][2][off]);
                bn[n][1] = *reinterpret_cast<const short8*>(&lds[cur][3][off]);
            }
#pragma unroll
            for (int m = 0; m < 2; m++) {
                u32x4 tn = *reinterpret_cast<u32x4*>(&am[m][0]) ^ 0x80008000u;
                short8 arn = *reinterpret_cast<short8*>(&tn);
#pragma unroll
                for (int n = 0; n < 4; n++) {
                    accRe[m][n] = __builtin_amdgcn_mfma_f32_16x16x32_bf16(am[m][0], bn[n][0], accRe[m][n], 0, 0, 0);
                    accRe[m][n] = __builtin_amdgcn_mfma_f32_16x16x32_bf16(am[m][1], bn[n][1], accRe[m][n], 0, 0, 0);
                    accIm[m][n] = __builtin_amdgcn_mfma_f32_16x16x32_bf16(am[m][1], bn[n][0], accIm[m][n], 0, 0, 0);
                    accIm[m][n] = __builtin_amdgcn_mfma_f32_16x16x32_bf16(arn,      bn[n][1], accIm[m][n], 0, 0, 0);
                }
            }
        }
        __builtin_amdgcn_s_setprio(0);
        asm volatile("s_waitcnt lgkmcnt(0)" ::: "memory"); // my buf[cur] reads retired before next barrier
        __builtin_amdgcn_sched_barrier(0);
    }
#undef STAGE5
    // ---- epilogue ----
    size_t ob = gb;
#pragma unroll
    for (int m = 0; m < 2; m++)
#pragma unroll
        for (int n = 0; n < 4; n++)
#pragma unroll
            for (int r = 0; r < 4; r++) {
                int a = a0 + wm * 32 + m * 16 + (lane >> 4) * 4 + r;
                int c = c0 + wn * 64 + n * 16 + (lane & 15);
                out[ob + ((size_t)a << 10) + c] = make_float2(accRe[m][n][r], accIm[m][n][r]);
            }
    // Mirror (lower) tile via LDS conj-transpose: two 64-col halves, coalesced out.
    if (ia != ic) {
        float2* mlds = reinterpret_cast<float2*>(&lds[0][0][0]);
#pragma unroll
        for (int h = 0; h < 2; ++h) {
            __syncthreads();
            if (wn == h) {
#pragma unroll
                for (int m = 0; m < 2; m++)
#pragma unroll
                    for (int n = 0; n < 4; n++)
#pragma unroll
                        for (int r = 0; r < 4; r++) {
                            int a_l = wm * 32 + m * 16 + (lane >> 4) * 4 + r;   // 0..127
                            int c_l = n * 16 + (lane & 15);                     // 0..63 within half
                            mlds[c_l * 131 + a_l] = make_float2(accRe[m][n][r], -accIm[m][n][r]);
                        }
            }
            __syncthreads();
#pragma unroll
            for (int i = 0; i < 16; ++i) {
                int p = tid + (i << 9);          // 8192 float2 = [64 c-rows][128 a-cols]
                int row = p >> 7, col = p & 127;
                out[ob + ((size_t)(c0 + h * 64 + row) << 10) + a0 + col] = mlds[row * 131 + col];
            }
        }
    }
}

extern "C" void kernel_launch(void* const* d_in, const int* in_sizes, int n_in,
                              void* d_out, int out_size, void* d_ws, size_t ws_size,
                              hipStream_t stream) {
    const float* x = (const float*)d_in[0];
    const float* weight = (const float*)d_in[1];
    const size_t psiBytes = (size_t)BATCH * DIM * sizeof(c32);       // 32 MB
    c32* psi = (c32*)d_ws;
    c32* G = (c32*)((char*)d_ws + psiBytes);                         // 19*32 c32
    unsigned short* Brt = (unsigned short*)((char*)d_ws + psiBytes + 65536);
    unsigned short* Bit = Brt + (size_t)BATCH * DIM;
    unsigned short* Art = Bit + (size_t)BATCH * DIM;
    unsigned short* Ait = Art + (size_t)BATCH * DIM;

    build_gates<<<1, 64, 0, stream>>>(weight, G);
    pass_a2<<<BATCH * 128, 256, 0, stream>>>(x, psi, G);            // gates 0..6
    pass_b2<<<BATCH * 128, 256, 0, stream>>>(psi, Brt, Bit, G);     // gates 7..18 -> bf16 [t][a]
    bt_t<<<dim3(16, 16, BATCH), 256, 0, stream>>>(Brt, Bit, Art, Ait);
    gram_mfma5c<<<144, 512, 0, stream>>>(Art, Ait, (float2*)d_out);
}

// Round 11
// 94.377 us; speedup vs baseline: 1.1426x; 1.0718x over previous
//
#include <hip/hip_runtime.h>
#include <hip/hip_bf16.h>

#define N_Q    20
#define DIM    (1 << N_Q)      // 1048576
#define BATCH  4
#define NGATES 19
#define L2OFF  117             // 6n-3 : second xyz layer offset
#define GSTRIDE 32             // per-gate: 16 g + 16 gs(swapped-negated)

typedef float2 c32;
typedef __attribute__((ext_vector_type(2))) float fv2;
typedef __attribute__((ext_vector_type(8))) short short8;
typedef __attribute__((ext_vector_type(4))) float f32x4;
typedef __attribute__((ext_vector_type(4))) unsigned int u32x4;

__device__ __forceinline__ c32 cmul(c32 a, c32 b) {
    return make_float2(fmaf(a.x, b.x, -a.y * b.y), fmaf(a.x, b.y, a.y * b.x));
}
__device__ __forceinline__ c32 cmadd(c32 acc, c32 a, c32 b) {
    acc.x = fmaf(a.x, b.x, fmaf(-a.y, b.y, acc.x));
    acc.y = fmaf(a.x, b.y, fmaf(a.y, b.x, acc.y));
    return acc;
}
__device__ __forceinline__ unsigned short f2bf(float f) {
    union { float f; unsigned u; } v; v.f = f;
    unsigned r = v.u + 0x7FFFu + ((v.u >> 16) & 1u);
    return (unsigned short)(r >> 16);
}
__device__ __forceinline__ unsigned pack_bf2(float re, float im) {
    return (unsigned)f2bf(re) | ((unsigned)f2bf(im) << 16);
}
__device__ __forceinline__ fv2 unpack_bf2(unsigned w) {
    union { unsigned u; float f; } lo, hi;
    lo.u = (w & 0xFFFFu) << 16;
    hi.u = w & 0xFFFF0000u;
    return (fv2){lo.f, hi.f};
}
__device__ __forceinline__ void gll16(const void* g, void* l) {
    __builtin_amdgcn_global_load_lds((const __attribute__((address_space(1))) void*)g,
                                     (__attribute__((address_space(3))) void*)l, 16, 0, 0);
}

__device__ void mm2(const c32 A[2][2], const c32 B[2][2], c32 C[2][2]) {
    for (int i = 0; i < 2; i++)
        for (int j = 0; j < 2; j++) {
            c32 s = make_float2(0.f, 0.f);
            for (int k = 0; k < 2; k++) s = cmadd(s, A[i][k], B[k][j]);
            C[i][j] = s;
        }
}
__device__ void mm4(const c32 A[4][4], const c32 B[4][4], c32 C[4][4]) {
    for (int i = 0; i < 4; i++)
        for (int j = 0; j < 4; j++) {
            c32 s = make_float2(0.f, 0.f);
            for (int k = 0; k < 4; k++) s = cmadd(s, A[i][k], B[k][j]);
            C[i][j] = s;
        }
}
__device__ void single_u(const float* w, int base, c32 U[2][2]) {
    const float WM = 0.63245553203367586640f;  // sqrt(2/5)
    float hx = w[base] * WM * 0.5f, hy = w[base + 1] * WM * 0.5f, hz = w[base + 2] * WM * 0.5f;
    float cx = cosf(hx), sx = sinf(hx);
    float cy = cosf(hy), sy = sinf(hy);
    float cz = cosf(hz), sz = sinf(hz);
    c32 RX[2][2] = {{{cx, 0.f}, {0.f, -sx}}, {{0.f, -sx}, {cx, 0.f}}};
    c32 RY[2][2] = {{{cy, 0.f}, {-sy, 0.f}}, {{sy, 0.f}, {cy, 0.f}}};
    c32 RZ[2][2] = {{{cz, -sz}, {0.f, 0.f}}, {{0.f, 0.f}, {cz, sz}}};
    c32 T[2][2];
    mm2(RY, RX, T);
    mm2(RZ, T, U);
}
__device__ void kron22(const c32 A[2][2], const c32 B[2][2], c32 K[4][4]) {
    for (int i = 0; i < 2; i++)
        for (int j = 0; j < 2; j++)
            for (int k = 0; k < 2; k++)
                for (int l = 0; l < 2; l++)
                    K[i * 2 + j][k * 2 + l] = cmul(A[i][k], B[j][l]);
}

// Build the 19 fused 4x4 staircase gates; emit both g and gs=(-g.y, g.x) tables.
__global__ void build_gates(const float* __restrict__ w, c32* __restrict__ G) {
    int q = threadIdx.x;
    if (q >= NGATES) return;
    const float WM = 0.63245553203367586640f;
    float hx = w[60 + 3 * q] * WM * 0.5f;
    float hy = w[61 + 3 * q] * WM * 0.5f;
    float hz = w[62 + 3 * q] * WM * 0.5f;
    float cx = cosf(hx), sx = sinf(hx);
    float cy = cosf(hy), sy = sinf(hy);
    float cz = cosf(hz), sz = sinf(hz);
    c32 RXX[4][4], RYY[4][4], RZZ[4][4];
    for (int i = 0; i < 4; i++)
        for (int j = 0; j < 4; j++) {
            RXX[i][j] = make_float2(0.f, 0.f);
            RYY[i][j] = make_float2(0.f, 0.f);
            RZZ[i][j] = make_float2(0.f, 0.f);
        }
    for (int i = 0; i < 4; i++) {
        RXX[i][i]     = make_float2(cx, 0.f);
        RXX[i][3 - i] = make_float2(0.f, -sx);
        RYY[i][i]     = make_float2(cy, 0.f);
    }
    RYY[0][3] = make_float2(0.f,  sy);
    RYY[1][2] = make_float2(0.f, -sy);
    RYY[2][1] = make_float2(0.f, -sy);
    RYY[3][0] = make_float2(0.f,  sy);
    RZZ[0][0] = make_float2(cz, -sz);
    RZZ[1][1] = make_float2(cz,  sz);
    RZZ[2][2] = make_float2(cz,  sz);
    RZZ[3][3] = make_float2(cz, -sz);
    c32 T[4][4], M[4][4];
    mm4(RYY, RXX, T);
    mm4(RZZ, T, M);

    c32 I2m[2][2] = {{{1.f, 0.f}, {0.f, 0.f}}, {{0.f, 0.f}, {1.f, 0.f}}};
    c32 Ua[2][2], Ub[2][2], Pre[4][4], Post[4][4];
    if (q == 0) {
        single_u(w, 0, Ua);
        single_u(w, 3, Ub);
        kron22(Ua, Ub, Pre);
    } else {
        single_u(w, 3 * (q + 1), Ub);
        kron22(I2m, Ub, Pre);
    }
    if (q == NGATES - 1) {
        single_u(w, L2OFF + 3 * 18, Ua);
        single_u(w, L2OFF + 3 * 19, Ub);
        kron22(Ua, Ub, Post);
    } else {
        single_u(w, L2OFF + 3 * q, Ua);
        kron22(Ua, I2m, Post);
    }
    c32 T2[4][4], Gq[4][4];
    mm4(M, Pre, T2);
    mm4(Post, T2, Gq);
    for (int i = 0; i < 4; i++)
        for (int j = 0; j < 4; j++) {
            c32 g = Gq[i][j];
            G[q * GSTRIDE + i * 4 + j]      = g;
            G[q * GSTRIDE + 16 + i * 4 + j] = make_float2(-g.y, g.x);
        }
}

// Packed complex 4x4 apply: x.xx*g + x.yy*gs -> 2 v_pk_fma per complex MAC.
__device__ __forceinline__ void apply4pk(const fv2 g[16], const fv2 gs[16],
                                         fv2& x0, fv2& x1, fv2& x2, fv2& x3) {
    fv2 a0 = (fv2)(x0[0]), b0 = (fv2)(x0[1]);
    fv2 a1 = (fv2)(x1[0]), b1 = (fv2)(x1[1]);
    fv2 a2 = (fv2)(x2[0]), b2 = (fv2)(x2[1]);
    fv2 a3 = (fv2)(x3[0]), b3 = (fv2)(x3[1]);
    fv2 r0 = a0 * g[0];  r0 += b0 * gs[0];  r0 += a1 * g[1];  r0 += b1 * gs[1];
    r0 += a2 * g[2];     r0 += b2 * gs[2];  r0 += a3 * g[3];  r0 += b3 * gs[3];
    fv2 r1 = a0 * g[4];  r1 += b0 * gs[4];  r1 += a1 * g[5];  r1 += b1 * gs[5];
    r1 += a2 * g[6];     r1 += b2 * gs[6];  r1 += a3 * g[7];  r1 += b3 * gs[7];
    fv2 r2 = a0 * g[8];  r2 += b0 * gs[8];  r2 += a1 * g[9];  r2 += b1 * gs[9];
    r2 += a2 * g[10];    r2 += b2 * gs[10]; r2 += a3 * g[11]; r2 += b3 * gs[11];
    fv2 r3 = a0 * g[12]; r3 += b0 * gs[12]; r3 += a1 * g[13]; r3 += b1 * gs[13];
    r3 += a2 * g[14];    r3 += b2 * gs[14]; r3 += a3 * g[15]; r3 += b3 * gs[15];
    x0 = r0; x1 = r1; x2 = r2; x3 = r3;
}
__device__ __forceinline__ void load_gate2(const fv2* __restrict__ gp, fv2 g[16], fv2 gs[16]) {
#pragma unroll
    for (int k = 0; k < 16; k++) { g[k] = gp[k]; gs[k] = gp[16 + k]; }
}
template <int LO>
__device__ __forceinline__ void gate_on32(fv2 v[32], const fv2 g[16], const fv2 gs[16]) {
#pragma unroll
    for (int m = 0; m < 8; ++m) {
        const int j0 = ((m >> LO) << (LO + 2)) | (m & ((1 << LO) - 1));
        const int s = 1 << LO;
        apply4pk(g, gs, v[j0], v[j0 + s], v[j0 + 2 * s], v[j0 + 3 * s]);
    }
}
template <int LO>
__device__ __forceinline__ void gate_on16(fv2* v, const fv2 g[16], const fv2 gs[16]) {
#pragma unroll
    for (int m = 0; m < 4; ++m) {
        const int j0 = ((m >> LO) << (LO + 2)) | (m & ((1 << LO) - 1));
        const int s = 1 << LO;
        apply4pk(g, gs, v[j0], v[j0 + s], v[j0 + 2 * s], v[j0 + 3 * s]);
    }
}

// XOR swizzle for 8192-elem LDS exchanges (verified <=4-way for all patterns used).
#define SIDX(l) ((l) ^ ((((l) >> 5) & 15)))

// Pass A2: gates 0..6 (psi bits 19..12). State = [256 rows = bits 19..12][4096 cols].
// Output psi now PACKED bf16 (u32 re|im) -- halves the psi link traffic.
__global__ __launch_bounds__(256) void pass_a2(const float* __restrict__ x,
                                               unsigned* __restrict__ psiB,
                                               const c32* __restrict__ Gall) {
    __shared__ __align__(16) char smem[65536];
    float* xs = (float*)smem;        // [256][32] f32, 16B-slot swizzled (32 KB)
    fv2* s = (fv2*)smem;             // 8192 fv2 exchange view (64 KB)
    const fv2* Gf = (const fv2*)Gall;
    int b = blockIdx.x >> 7;
    int c0 = (blockIdx.x & 127) << 5;
    const float* xp = x + ((size_t)b << 20) + c0;
    unsigned* ppb = psiB + ((size_t)b << 20) + c0;
    int t = threadIdx.x;
#pragma unroll
    for (int i = 0; i < 8; ++i) {
        int f4 = t + (i << 8);
        int row = f4 >> 3, sl = f4 & 7;
        float4 v = *reinterpret_cast<const float4*>(xp + (size_t)row * 4096 + sl * 4);
        reinterpret_cast<float4*>(xs)[row * 8 + (sl ^ (row & 7))] = v;
    }
    __syncthreads();
    int col = t & 31, rlow = t >> 5;
    fv2 v[32], g[16], gs[16];
#pragma unroll
    for (int j = 0; j < 32; ++j) {
        int row = (j << 3) | rlow;
        float re = xs[row * 32 + ((((col >> 2) ^ (row & 7)) << 2) | (col & 3))];
        v[j] = (fv2){re, 0.f};
    }
    __syncthreads();
    load_gate2(Gf + 0 * GSTRIDE, g, gs);  gate_on32<3>(v, g, gs);
    load_gate2(Gf + 1 * GSTRIDE, g, gs);  gate_on32<2>(v, g, gs);
    load_gate2(Gf + 2 * GSTRIDE, g, gs);  gate_on32<1>(v, g, gs);
    load_gate2(Gf + 3 * GSTRIDE, g, gs);  gate_on32<0>(v, g, gs);
#pragma unroll
    for (int j = 0; j < 32; ++j) {
        int l = ((((j << 3) | rlow) << 5)) | col;
        s[SIDX(l)] = v[j];
    }
    __syncthreads();
    int rhi = t >> 5;
#pragma unroll
    for (int rtop = 0; rtop < 2; ++rtop)
#pragma unroll
        for (int j = 0; j < 16; ++j) {
            int row = (rtop << 7) | (rhi << 4) | j;
            int l = (row << 5) | col;
            v[rtop * 16 + j] = s[SIDX(l)];
        }
    load_gate2(Gf + 4 * GSTRIDE, g, gs);  gate_on16<2>(v, g, gs);  gate_on16<2>(v + 16, g, gs);
    load_gate2(Gf + 5 * GSTRIDE, g, gs);  gate_on16<1>(v, g, gs);  gate_on16<1>(v + 16, g, gs);
    load_gate2(Gf + 6 * GSTRIDE, g, gs);  gate_on16<0>(v, g, gs);  gate_on16<0>(v + 16, g, gs);
#pragma unroll
    for (int rtop = 0; rtop < 2; ++rtop)
#pragma unroll
        for (int j = 0; j < 16; ++j) {
            int row = (rtop << 7) | (rhi << 4) | j;
            fv2 val = v[rtop * 16 + j];
            ppb[(size_t)row * 4096 + col] = pack_bf2(val[0], val[1]);
        }
}

// Pass B2: gates 7..18 (psi bits 12..0). Reads packed-bf16 psi; 3 register
// phases, 2 LDS exchanges; writes planar bf16 [t][a] (Brt, Bit).
__global__ __launch_bounds__(256) void pass_b2(const unsigned* __restrict__ psiB,
                                               unsigned short* __restrict__ Brt,
                                               unsigned short* __restrict__ Bit,
                                               const c32* __restrict__ Gall) {
    __shared__ fv2 s[8192];
    const fv2* Gf = (const fv2*)Gall;
    int b = blockIdx.x >> 7;
    int chunk = blockIdx.x & 127;
    const unsigned* ppb = psiB + ((size_t)b << 20) + ((size_t)chunk << 13);
    int t = threadIdx.x;
    fv2 v[32], g[16], gs[16];
#pragma unroll
    for (int j = 0; j < 32; ++j) v[j] = unpack_bf2(ppb[(j << 8) | t]);
    load_gate2(Gf + 7 * GSTRIDE, g, gs);   gate_on32<3>(v, g, gs);
    load_gate2(Gf + 8 * GSTRIDE, g, gs);   gate_on32<2>(v, g, gs);
    load_gate2(Gf + 9 * GSTRIDE, g, gs);   gate_on32<1>(v, g, gs);
    load_gate2(Gf + 10 * GSTRIDE, g, gs);  gate_on32<0>(v, g, gs);
#pragma unroll
    for (int j = 0; j < 32; ++j) { int l = (j << 8) | t; s[SIDX(l)] = v[j]; }
    __syncthreads();
    int hi2 = (t >> 4) << 9, lo2 = t & 15;
#pragma unroll
    for (int j = 0; j < 32; ++j) { int l = hi2 | (j << 4) | lo2; v[j] = s[SIDX(l)]; }
    load_gate2(Gf + 11 * GSTRIDE, g, gs);  gate_on32<3>(v, g, gs);
    load_gate2(Gf + 12 * GSTRIDE, g, gs);  gate_on32<2>(v, g, gs);
    load_gate2(Gf + 13 * GSTRIDE, g, gs);  gate_on32<1>(v, g, gs);
    load_gate2(Gf + 14 * GSTRIDE, g, gs);  gate_on32<0>(v, g, gs);
    __syncthreads();
#pragma unroll
    for (int j = 0; j < 32; ++j) { int l = hi2 | (j << 4) | lo2; s[SIDX(l)] = v[j]; }
    __syncthreads();
#pragma unroll
    for (int j = 0; j < 32; ++j) { int l = (t << 5) | j; v[j] = s[SIDX(l)]; }
    load_gate2(Gf + 15 * GSTRIDE, g, gs);  gate_on32<3>(v, g, gs);
    load_gate2(Gf + 16 * GSTRIDE, g, gs);  gate_on32<2>(v, g, gs);
    load_gate2(Gf + 17 * GSTRIDE, g, gs);  gate_on32<1>(v, g, gs);
    load_gate2(Gf + 18 * GSTRIDE, g, gs);  gate_on32<0>(v, g, gs);
    size_t off = ((size_t)b << 20) + ((size_t)chunk << 13) + ((size_t)t << 5);
#pragma unroll
    for (int p = 0; p < 4; ++p) {
        unsigned short rr[8], ri[8];
#pragma unroll
        for (int i = 0; i < 8; ++i) {
            rr[i] = f2bf(v[8 * p + i][0]);
            ri[i] = f2bf(v[8 * p + i][1]);
        }
        *reinterpret_cast<float4*>(Brt + off + 8 * p) = *reinterpret_cast<float4*>(rr);
        *reinterpret_cast<float4*>(Bit + off + 8 * p) = *reinterpret_cast<float4*>(ri);
    }
}

// bf16 transpose: B[t][a] -> A[a][t] for both planes, merged as u32 in LDS.
__global__ __launch_bounds__(256) void bt_t(const unsigned short* __restrict__ Brt,
                                            const unsigned short* __restrict__ Bit,
                                            unsigned short* __restrict__ Art,
                                            unsigned short* __restrict__ Ait) {
    __shared__ unsigned lds32[64 * 66];
    int b  = blockIdx.z;
    int t0 = blockIdx.x * 64;
    int a0 = blockIdx.y * 64;
    size_t gb = (size_t)b << 20;
#pragma unroll
    for (int h = 0; h < 2; ++h) {
        int p = threadIdx.x + h * 256;
        int r = p >> 3, cq = p & 7;
        size_t src = gb + (size_t)(t0 + r) * 1024 + a0 + cq * 8;
        float4 fr = *reinterpret_cast<const float4*>(Brt + src);
        float4 fi = *reinterpret_cast<const float4*>(Bit + src);
        const unsigned short* ur = reinterpret_cast<const unsigned short*>(&fr);
        const unsigned short* ui = reinterpret_cast<const unsigned short*>(&fi);
#pragma unroll
        for (int i = 0; i < 8; ++i)
            lds32[r * 66 + cq * 8 + i] = (unsigned)ur[i] | ((unsigned)ui[i] << 16);
    }
    __syncthreads();
#pragma unroll
    for (int h = 0; h < 2; ++h) {
        int q = threadIdx.x + h * 256;
        int a = q >> 3, tq = q & 7;
        unsigned short rr[8], ri[8];
#pragma unroll
        for (int i = 0; i < 8; ++i) {
            unsigned w = lds32[(tq * 8 + i) * 66 + a];
            rr[i] = (unsigned short)(w & 0xFFFF);
            ri[i] = (unsigned short)(w >> 16);
        }
        size_t dst = gb + (size_t)(a0 + a) * 1024 + t0 + tq * 8;
        *reinterpret_cast<float4*>(Art + dst) = *reinterpret_cast<float4*>(rr);
        *reinterpret_cast<float4*>(Ait + dst) = *reinterpret_cast<float4*>(ri);
    }
}

// gram_mfma5c: unchanged from round 10 (near structure-practical floor for this
// problem size; see r10 post-mortem).
__global__ __launch_bounds__(512) void gram_mfma5c(const unsigned short* __restrict__ Art,
                                                   const unsigned short* __restrict__ Ait,
                                                   float2* __restrict__ out) {
    __shared__ __align__(16) unsigned short lds[2][4][8192];   // 128 KB
    int hw = blockIdx.x;
    int virt = (hw & 7) * 18 + (hw >> 3);        // bijective: 144 = 8*18, XCD-chunked
    int b = virt / 36;
    int rem = virt - b * 36;                     // triangular decode over 8x8, ia <= ic
    int ia = 0;
    while (rem >= 8 - ia) { rem -= 8 - ia; ++ia; }
    int ic = ia + rem;
    int a0 = ia * 128, c0 = ic * 128;
    int tid = threadIdx.x;
    int lane = tid & 63, w = tid >> 6;           // 8 waves
    int wm = w & 3, wn = w >> 2;                 // wave-tile: rows wm*32, cols wn*64
    int arr = w >> 1, half = w & 1;
    const unsigned short* sp = (arr & 1) ? Ait : Art;
    int prow = (arr < 2) ? a0 : c0;
    int srow = lane >> 3, sslot = lane & 7;
    size_t gb = (size_t)b << 20;

    f32x4 accRe[2][4], accIm[2][4];
#pragma unroll
    for (int m = 0; m < 2; m++)
#pragma unroll
        for (int n = 0; n < 4; n++) { accRe[m][n] = (f32x4)0.f; accIm[m][n] = (f32x4)0.f; }

#define STAGE5(KT, BUF)                                                                   \
    {                                                                                     \
        _Pragma("unroll")                                                                 \
        for (int i = 0; i < 8; ++i) {                                                     \
            int r = (half << 6) | (i << 3) | srow;                                        \
            int sl = sslot ^ srow;                                                        \
            const unsigned short* gp = sp + gb + ((size_t)(prow + r) << 10) + (KT) * 64 + sl * 8; \
            gll16(gp, &lds[BUF][arr][((half << 6) | (i << 3)) * 64 + lane * 8]);          \
        }                                                                                 \
    }

    STAGE5(0, 0);
    for (int kt = 0; kt < 16; ++kt) {
        int cur = kt & 1;
        asm volatile("s_waitcnt vmcnt(0)" ::: "memory");
        __builtin_amdgcn_s_barrier();
        __builtin_amdgcn_sched_barrier(0);
        if (kt < 15) STAGE5(kt + 1, cur ^ 1);
        __builtin_amdgcn_s_setprio(1);
#pragma unroll
        for (int kk = 0; kk < 2; ++kk) {
            int sbase = kk * 4 + (lane >> 4);    // 16B-slot index 0..7
            short8 am[2][2], bn[4][2];
#pragma unroll
            for (int m = 0; m < 2; m++) {
                int r = wm * 32 + m * 16 + (lane & 15);
                int off = r * 64 + ((sbase ^ (r & 7)) << 3);
                am[m][0] = *reinterpret_cast<const short8*>(&lds[cur][0][off]);
                am[m][1] = *reinterpret_cast<const short8*>(&lds[cur][1][off]);
            }
#pragma unroll
            for (int n = 0; n < 4; n++) {
                int r = wn * 64 + n * 16 + (lane & 15);
                int off = r * 64 + ((sbase ^ (r & 7)) << 3);
                bn[n][0] = *reinterpret_cast<const short8*>(&lds[cur][2][off]);
                bn[n][1] = *reinterpret_cast<const short8*>(&lds[cur][3][off]);
            }
#pragma unroll
            for (int m = 0; m < 2; m++) {
                u32x4 tn = *reinterpret_cast<u32x4*>(&am[m][0]) ^ 0x80008000u;
                short8 arn = *reinterpret_cast<short8*>(&tn);
#pragma unroll
                for (int n = 0; n < 4; n++) {
                    accRe[m][n] = __builtin_amdgcn_mfma_f32_16x16x32_bf16(am[m][0], bn[n][0], accRe[m][n], 0, 0, 0);
                    accRe[m][n] = __builtin_amdgcn_mfma_f32_16x16x32_bf16(am[m][1], bn[n][1], accRe[m][n], 0, 0, 0);
                    accIm[m][n] = __builtin_amdgcn_mfma_f32_16x16x32_bf16(am[m][1], bn[n][0], accIm[m][n], 0, 0, 0);
                    accIm[m][n] = __builtin_amdgcn_mfma_f32_16x16x32_bf16(arn,      bn[n][1], accIm[m][n], 0, 0, 0);
                }
            }
        }
        __builtin_amdgcn_s_setprio(0);
        asm volatile("s_waitcnt lgkmcnt(0)" ::: "memory");
        __builtin_amdgcn_sched_barrier(0);
    }
#undef STAGE5
    // ---- epilogue ----
    size_t ob = gb;
#pragma unroll
    for (int m = 0; m < 2; m++)
#pragma unroll
        for (int n = 0; n < 4; n++)
#pragma unroll
            for (int r = 0; r < 4; r++) {
                int a = a0 + wm * 32 + m * 16 + (lane >> 4) * 4 + r;
                int c = c0 + wn * 64 + n * 16 + (lane & 15);
                out[ob + ((size_t)a << 10) + c] = make_float2(accRe[m][n][r], accIm[m][n][r]);
            }
    if (ia != ic) {
        float2* mlds = reinterpret_cast<float2*>(&lds[0][0][0]);
#pragma unroll
        for (int h = 0; h < 2; ++h) {
            __syncthreads();
            if (wn == h) {
#pragma unroll
                for (int m = 0; m < 2; m++)
#pragma unroll
                    for (int n = 0; n < 4; n++)
#pragma unroll
                        for (int r = 0; r < 4; r++) {
                            int a_l = wm * 32 + m * 16 + (lane >> 4) * 4 + r;   // 0..127
                            int c_l = n * 16 + (lane & 15);                     // 0..63 within half
                            mlds[c_l * 131 + a_l] = make_float2(accRe[m][n][r], -accIm[m][n][r]);
                        }
            }
            __syncthreads();
#pragma unroll
            for (int i = 0; i < 16; ++i) {
                int p = tid + (i << 9);          // 8192 float2 = [64 c-rows][128 a-cols]
                int row = p >> 7, col = p & 127;
                out[ob + ((size_t)(c0 + h * 64 + row) << 10) + a0 + col] = mlds[row * 131 + col];
            }
        }
    }
}

extern "C" void kernel_launch(void* const* d_in, const int* in_sizes, int n_in,
                              void* d_out, int out_size, void* d_ws, size_t ws_size,
                              hipStream_t stream) {
    const float* x = (const float*)d_in[0];
    const float* weight = (const float*)d_in[1];
    const size_t psiBytes = (size_t)BATCH * DIM * sizeof(unsigned);  // 16 MB (packed bf16)
    unsigned* psiB = (unsigned*)d_ws;
    c32* G = (c32*)((char*)d_ws + psiBytes);                         // 19*32 c32
    unsigned short* Brt = (unsigned short*)((char*)d_ws + psiBytes + 65536);
    unsigned short* Bit = Brt + (size_t)BATCH * DIM;
    unsigned short* Art = Bit + (size_t)BATCH * DIM;
    unsigned short* Ait = Art + (size_t)BATCH * DIM;

    build_gates<<<1, 64, 0, stream>>>(weight, G);
    pass_a2<<<BATCH * 128, 256, 0, stream>>>(x, psiB, G);            // gates 0..6 -> packed bf16 psi
    pass_b2<<<BATCH * 128, 256, 0, stream>>>(psiB, Brt, Bit, G);     // gates 7..18 -> bf16 [t][a]
    bt_t<<<dim3(16, 16, BATCH), 256, 0, stream>>>(Brt, Bit, Art, Ait);
    gram_mfma5c<<<144, 512, 0, stream>>>(Art, Ait, (float2*)d_out);
}